// Round 1
// baseline (3712.018 us; speedup 1.0000x reference)
//
#include <hip/hip_runtime.h>
#include <math.h>

#define T_ 16
#define N_ 6400
#define E_ 65536
#define IN_ 128
#define ED_ 16
#define H_ 256
#define B_ 64
#define HEADS_ 8
#define L_ 2
#define DFF_ 2048
#define OUT_ 8
#define DH_ 32
#define S_ 17
#define EPB_ 64

// ---------------- utility ----------------
__global__ void zero_k(float* __restrict__ p, long n) {
  long i = (long)blockIdx.x * 256 + threadIdx.x;
  if (i < n) p[i] = 0.f;
}

// ---------------- GEMM: O[M,Nc] = A[M,K] @ W[K,Nc] + bias, epilogue ----------------
// M mult of 64, Nc mult of 64, K mult of 16. 64x64 tile, 256 thr, 4x4/thread.
// EP: 0 none, 1 relu, 2 tanh
template <int EP>
__launch_bounds__(256) __global__
void gemm_k(const float* __restrict__ Abase, long az,
            const float* __restrict__ W, const float* __restrict__ bias,
            float* __restrict__ Obase, long oz, int K, int Nc) {
  const float* A = Abase + (long)blockIdx.z * az;
  float* O = Obase + (long)blockIdx.z * oz;
  const int n0 = blockIdx.x * 64;
  const int m0 = blockIdx.y * 64;
  const int tid = threadIdx.x;
  const int tx = tid & 15, ty = tid >> 4;
  __shared__ float As[16][64];
  __shared__ float Ws[16][64];
  float acc[4][4] = {{0.f, 0.f, 0.f, 0.f}, {0.f, 0.f, 0.f, 0.f},
                     {0.f, 0.f, 0.f, 0.f}, {0.f, 0.f, 0.f, 0.f}};
  const int ar = tid >> 2;         // 0..63 row within tile
  const int ak = (tid & 3) << 2;   // 0,4,8,12
  const int wr = tid >> 4;         // 0..15
  const int wc = (tid & 15) << 2;  // 0..60
  for (int k0 = 0; k0 < K; k0 += 16) {
    const float4 av = *(const float4*)(A + (long)(m0 + ar) * K + k0 + ak);
    const float4 wv = *(const float4*)(W + (long)(k0 + wr) * Nc + n0 + wc);
    __syncthreads();
    As[ak + 0][ar] = av.x;
    As[ak + 1][ar] = av.y;
    As[ak + 2][ar] = av.z;
    As[ak + 3][ar] = av.w;
    *(float4*)(&Ws[wr][wc]) = wv;
    __syncthreads();
#pragma unroll
    for (int kk = 0; kk < 16; ++kk) {
      const float4 a4 = *(const float4*)(&As[kk][ty << 2]);
      const float4 b4 = *(const float4*)(&Ws[kk][tx << 2]);
      const float aa[4] = {a4.x, a4.y, a4.z, a4.w};
      const float bb[4] = {b4.x, b4.y, b4.z, b4.w};
#pragma unroll
      for (int i = 0; i < 4; ++i)
#pragma unroll
        for (int j = 0; j < 4; ++j) acc[i][j] = fmaf(aa[i], bb[j], acc[i][j]);
    }
  }
#pragma unroll
  for (int i = 0; i < 4; ++i) {
    const int m = m0 + (ty << 2) + i;
    float o[4];
#pragma unroll
    for (int j = 0; j < 4; ++j) {
      float v = acc[i][j];
      if (bias) v += bias[n0 + (tx << 2) + j];
      if (EP == 1) v = fmaxf(v, 0.f);
      if (EP == 2) v = tanhf(v);
      o[j] = v;
    }
    *(float4*)(O + (long)m * Nc + n0 + (tx << 2)) = make_float4(o[0], o[1], o[2], o[3]);
  }
}

// ---------------- edge scatter: agg[dst] += xw[src] + ea @ Wn_bot ----------------
__launch_bounds__(256) __global__
void scatter_k(const float* __restrict__ xw, const float* __restrict__ eab,
               const int* __restrict__ eib, const float* __restrict__ wnb,
               float* __restrict__ agg, float* __restrict__ cnt, int t0) {
  const int z = blockIdx.z;
  const int t = t0 + z;
  const float* ea = eab + (long)t * E_ * ED_;
  const int* srcp = eib + (long)t * 2 * E_;
  const int* dstp = srcp + E_;
  const float* xwz = xw + (long)z * N_ * H_;
  float* aggz = agg + (long)z * N_ * H_;
  float* cntz = cnt + (long)z * N_;
  __shared__ float wsh[ED_][H_];
  __shared__ float eash[EPB_][ED_];
  __shared__ int ssrc[EPB_], sdst[EPB_];
  const int tid = threadIdx.x;
  const int e0 = blockIdx.x * EPB_;
  for (int i = tid; i < ED_ * H_; i += 256) wsh[i >> 8][i & 255] = wnb[i];
  for (int i = tid; i < EPB_ * ED_; i += 256) eash[i >> 4][i & 15] = ea[(long)e0 * ED_ + i];
  if (tid < EPB_) {
    ssrc[tid] = srcp[e0 + tid];
    sdst[tid] = dstp[e0 + tid];
  }
  __syncthreads();
  const int c = tid;
  if (tid < EPB_) atomicAdd(&cntz[sdst[tid]], 1.f);
#pragma unroll 1
  for (int j = 0; j < EPB_; ++j) {
    float v = xwz[(long)ssrc[j] * H_ + c];
#pragma unroll
    for (int k = 0; k < ED_; ++k) v = fmaf(eash[j][k], wsh[k][c], v);
    atomicAdd(&aggz[(long)sdst[j] * H_ + c], v);
  }
}

// ---------------- node update: h = LN(relu(agg/max(cnt,1) + root)) ----------------
__launch_bounds__(256) __global__
void node_ln_k(const float* __restrict__ agg, const float* __restrict__ cnt,
               const float* __restrict__ root, const float* __restrict__ g,
               const float* __restrict__ bb, float* __restrict__ outh) {
  const long z = blockIdx.y;
  const int n = blockIdx.x, c = threadIdx.x;
  const long row = (z * N_ + n) * (long)H_;
  float v = agg[row + c] / fmaxf(cnt[z * N_ + n], 1.f) + root[row + c];
  v = fmaxf(v, 0.f);
  __shared__ float rs[256], rq[256];
  rs[c] = v;
  rq[c] = v * v;
  __syncthreads();
  for (int s = 128; s > 0; s >>= 1) {
    if (c < s) {
      rs[c] += rs[c + s];
      rq[c] += rq[c + s];
    }
    __syncthreads();
  }
  const float mean = rs[0] * (1.f / H_);
  const float var = rq[0] * (1.f / H_) - mean * mean;
  outh[row + c] = (v - mean) * rsqrtf(var + 1e-5f) * g[c] + bb[c];
}

// ---------------- pooling ----------------
__launch_bounds__(256) __global__
void score_k(const float* __restrict__ tnh, const float* __restrict__ sw,
             const float* __restrict__ sb, float* __restrict__ sbuf) {
  const long z = blockIdx.y;
  const int n = blockIdx.x, c = threadIdx.x;
  float p = tnh[(z * N_ + n) * (long)H_ + c] * sw[c];
  __shared__ float rs[256];
  rs[c] = p;
  __syncthreads();
  for (int s = 128; s > 0; s >>= 1) {
    if (c < s) rs[c] += rs[c + s];
    __syncthreads();
  }
  if (c == 0) sbuf[z * N_ + n] = rs[0] + sb[0];
}

__device__ __forceinline__ unsigned enc_f(float f) {
  unsigned u = __float_as_uint(f);
  return (u & 0x80000000u) ? ~u : (u | 0x80000000u);
}
__device__ __forceinline__ float dec_f(unsigned u) {
  return (u & 0x80000000u) ? __uint_as_float(u ^ 0x80000000u) : __uint_as_float(~u);
}

__global__ void segmax_k(const float* __restrict__ sbuf, const int* __restrict__ batchb,
                         unsigned* __restrict__ smax, int t0) {
  const int z = blockIdx.y;
  const int n = blockIdx.x * 256 + threadIdx.x;
  const int t = t0 + z;
  const int g = batchb[(long)t * N_ + n];
  atomicMax(&smax[z * B_ + g], enc_f(sbuf[(long)z * N_ + n]));
}

__global__ void expsum_k(float* __restrict__ sbuf, const int* __restrict__ batchb,
                         const unsigned* __restrict__ smax, float* __restrict__ esum, int t0) {
  const int z = blockIdx.y;
  const int n = blockIdx.x * 256 + threadIdx.x;
  const int t = t0 + z;
  const int g = batchb[(long)t * N_ + n];
  const float e = expf(sbuf[(long)z * N_ + n] - dec_f(smax[z * B_ + g]));
  sbuf[(long)z * N_ + n] = e;
  atomicAdd(&esum[z * B_ + g], e);
}

__launch_bounds__(256) __global__
void poolscat_k(const float* __restrict__ h, const float* __restrict__ ebuf,
                const float* __restrict__ esum, const int* __restrict__ batchb,
                float* __restrict__ pooled, int t0) {
  const int z = blockIdx.y;
  const int t = t0 + z;
  const int n = blockIdx.x, c = threadIdx.x;
  const int g = batchb[(long)t * N_ + n];
  const float w = ebuf[(long)z * N_ + n] / esum[z * B_ + g];
  atomicAdd(&pooled[((long)t * B_ + g) * H_ + c], h[((long)z * N_ + n) * H_ + c] * w);
}

// ---------------- transformer ----------------
__global__ void build_seq_k(const float* __restrict__ pooled, const float* __restrict__ cls,
                            const float* __restrict__ pos, float* __restrict__ seq) {
  const int s = blockIdx.x, b = blockIdx.y, c = threadIdx.x;
  const float v = (s == 0) ? cls[c] : pooled[(((long)(s - 1)) * B_ + b) * H_ + c];
  seq[((long)b * S_ + s) * H_ + c] = v + pos[(long)s * H_ + c];
}

__launch_bounds__(256) __global__
void attn_k(const float* __restrict__ qkv, float* __restrict__ obuf) {
  const int b = blockIdx.x, h = blockIdx.y;
  __shared__ float qs[S_][DH_], ks[S_][DH_], vs[S_][DH_], att[S_][S_];
  const int tid = threadIdx.x;
  for (int i = tid; i < S_ * DH_; i += 256) {
    const int s = i / DH_, d = i % DH_;
    const long base = ((long)b * S_ + s) * (3 * H_) + h * DH_ + d;
    qs[s][d] = qkv[base];
    ks[s][d] = qkv[base + H_];
    vs[s][d] = qkv[base + 2 * H_];
  }
  __syncthreads();
  for (int i = tid; i < S_ * S_; i += 256) {
    const int r = i / S_, c2 = i % S_;
    float acc = 0.f;
#pragma unroll
    for (int d = 0; d < DH_; ++d) acc = fmaf(qs[r][d], ks[c2][d], acc);
    att[r][c2] = acc * 0.17677669529663687f;  // 1/sqrt(32)
  }
  __syncthreads();
  if (tid < S_) {
    float m = -1e30f;
    for (int j = 0; j < S_; ++j) m = fmaxf(m, att[tid][j]);
    float sum = 0.f;
    for (int j = 0; j < S_; ++j) {
      const float e = expf(att[tid][j] - m);
      att[tid][j] = e;
      sum += e;
    }
    const float inv = 1.f / sum;
    for (int j = 0; j < S_; ++j) att[tid][j] *= inv;
  }
  __syncthreads();
  for (int i = tid; i < S_ * DH_; i += 256) {
    const int s = i / DH_, d = i % DH_;
    float acc = 0.f;
#pragma unroll
    for (int j = 0; j < S_; ++j) acc = fmaf(att[s][j], vs[j][d], acc);
    obuf[((long)b * S_ + s) * H_ + h * DH_ + d] = acc;
  }
}

__launch_bounds__(256) __global__
void resid_ln_k(float* __restrict__ seq, const float* __restrict__ add,
                const float* __restrict__ g, const float* __restrict__ bb) {
  const int row = blockIdx.x, c = threadIdx.x;
  const float v = seq[(long)row * H_ + c] + add[(long)row * H_ + c];
  __shared__ float rs[256], rq[256];
  rs[c] = v;
  rq[c] = v * v;
  __syncthreads();
  for (int s = 128; s > 0; s >>= 1) {
    if (c < s) {
      rs[c] += rs[c + s];
      rq[c] += rq[c + s];
    }
    __syncthreads();
  }
  const float mean = rs[0] * (1.f / H_);
  const float var = rq[0] * (1.f / H_) - mean * mean;
  seq[(long)row * H_ + c] = (v - mean) * rsqrtf(var + 1e-5f) * g[c] + bb[c];
}

__launch_bounds__(256) __global__
void head_k(const float* __restrict__ seq, const float* __restrict__ hw,
            const float* __restrict__ hb, float* __restrict__ out) {
  const int b = blockIdx.x, c = threadIdx.x;
  const float x = seq[(long)b * S_ * H_ + c];
  __shared__ float rs[256];
  for (int o = 0; o < OUT_; ++o) {
    rs[c] = x * hw[c * OUT_ + o];
    __syncthreads();
    for (int s = 128; s > 0; s >>= 1) {
      if (c < s) rs[c] += rs[c + s];
      __syncthreads();
    }
    if (c == 0) {
      const float v = rs[0] + hb[o];
      out[b * OUT_ + o] = fmaxf(v, 0.f) + log1pf(expf(-fabsf(v)));  // softplus
    }
    __syncthreads();
  }
}

// ---------------- launcher ----------------
extern "C" void kernel_launch(void* const* d_in, const int* in_sizes, int n_in,
                              void* d_out, int out_size, void* d_ws, size_t ws_size,
                              hipStream_t stream) {
  const float* x = (const float*)d_in[0];
  const float* ea = (const float*)d_in[1];
  const int* ei = (const int*)d_in[2];
  const int* batch = (const int*)d_in[3];
  const float* nw0 = (const float*)d_in[4];
  const float* nb0 = (const float*)d_in[5];
  const float* rw0 = (const float*)d_in[6];
  const float* rb0 = (const float*)d_in[7];
  const float* lg0 = (const float*)d_in[8];
  const float* lb0 = (const float*)d_in[9];
  const float* nw1 = (const float*)d_in[10];
  const float* nb1 = (const float*)d_in[11];
  const float* rw1 = (const float*)d_in[12];
  const float* rb1 = (const float*)d_in[13];
  const float* lg1 = (const float*)d_in[14];
  const float* lb1 = (const float*)d_in[15];
  const float* ppw = (const float*)d_in[16];
  const float* ppb = (const float*)d_in[17];
  const float* psw = (const float*)d_in[18];
  const float* psb = (const float*)d_in[19];
  const float* pos = (const float*)d_in[20];
  const float* cls = (const float*)d_in[21];
  const float* qkvw = (const float*)d_in[22];
  const float* qkvbias = (const float*)d_in[23];
  const float* outw = (const float*)d_in[24];
  const float* outb = (const float*)d_in[25];
  const float* f1w = (const float*)d_in[26];
  const float* f1b = (const float*)d_in[27];
  const float* f2w = (const float*)d_in[28];
  const float* f2b = (const float*)d_in[29];
  const float* l1g = (const float*)d_in[30];
  const float* l1b = (const float*)d_in[31];
  const float* l2g = (const float*)d_in[32];
  const float* l2b = (const float*)d_in[33];
  const float* hw = (const float*)d_in[34];
  const float* hb = (const float*)d_in[35];
  float* out = (float*)d_out;

  float* ws = (float*)d_ws;
  const long fixedf = (long)T_ * B_ * H_ + (long)B_ * S_ * H_ + (long)B_ * S_ * 3 * H_ +
                      (long)B_ * S_ * H_ + (long)B_ * S_ * DFF_;
  const long perday = 4L * N_ * H_ + 2L * N_ + 2L * B_;
  int DT = 16;
  while (DT > 1 && (size_t)(fixedf + (long)DT * perday) * 4 > ws_size) DT >>= 1;

  float* pooled = ws;
  float* seq = pooled + (long)T_ * B_ * H_;
  float* qkvbuf = seq + (long)B_ * S_ * H_;
  float* obuf = qkvbuf + (long)B_ * S_ * 3 * H_;
  float* ffbuf = obuf + (long)B_ * S_ * H_;
  float* bufA = ffbuf + (long)B_ * S_ * DFF_;
  float* bufR = bufA + (long)DT * N_ * H_;
  float* bufD = bufR + (long)DT * N_ * H_;
  float* bufG = bufD + (long)DT * N_ * H_;
  float* cnt = bufG + (long)DT * N_ * H_;
  float* sbuf = cnt + (long)DT * N_;
  unsigned* smax = (unsigned*)(sbuf + (long)DT * N_);
  float* esum = (float*)(smax + (long)DT * B_);

  auto zero = [&](float* p, long n) {
    zero_k<<<dim3((unsigned)((n + 255) / 256)), 256, 0, stream>>>(p, n);
  };

  zero(pooled, (long)T_ * B_ * H_);

  const long NH = (long)N_ * H_;
  for (int t0 = 0; t0 < T_; t0 += DT) {
    const int zc = DT;
    // ----- conv layer 0 -----
    zero(bufG, (long)zc * NH);
    zero(cnt, (long)zc * N_);
    gemm_k<0><<<dim3(H_ / 64, N_ / 64, zc), 256, 0, stream>>>(
        x + (long)t0 * N_ * IN_, (long)N_ * IN_, nw0, nb0, bufA, NH, IN_, H_);
    gemm_k<0><<<dim3(H_ / 64, N_ / 64, zc), 256, 0, stream>>>(
        x + (long)t0 * N_ * IN_, (long)N_ * IN_, rw0, rb0, bufR, NH, IN_, H_);
    scatter_k<<<dim3(E_ / EPB_, 1, zc), 256, 0, stream>>>(bufA, ea, ei, nw0 + (long)IN_ * H_,
                                                          bufG, cnt, t0);
    node_ln_k<<<dim3(N_, zc), 256, 0, stream>>>(bufG, cnt, bufR, lg0, lb0, bufD);
    // ----- conv layer 1 -----
    zero(bufG, (long)zc * NH);
    zero(cnt, (long)zc * N_);
    gemm_k<0><<<dim3(H_ / 64, N_ / 64, zc), 256, 0, stream>>>(bufD, NH, nw1, nb1, bufA, NH, H_, H_);
    gemm_k<0><<<dim3(H_ / 64, N_ / 64, zc), 256, 0, stream>>>(bufD, NH, rw1, rb1, bufR, NH, H_, H_);
    scatter_k<<<dim3(E_ / EPB_, 1, zc), 256, 0, stream>>>(bufA, ea, ei, nw1 + (long)H_ * H_,
                                                          bufG, cnt, t0);
    node_ln_k<<<dim3(N_, zc), 256, 0, stream>>>(bufG, cnt, bufR, lg1, lb1, bufA);
    // ----- pooling -----
    gemm_k<2><<<dim3(H_ / 64, N_ / 64, zc), 256, 0, stream>>>(bufA, NH, ppw, ppb, bufG, NH, H_, H_);
    score_k<<<dim3(N_, zc), 256, 0, stream>>>(bufG, psw, psb, sbuf);
    zero((float*)smax, (long)zc * B_);
    zero(esum, (long)zc * B_);
    segmax_k<<<dim3(N_ / 256, zc), 256, 0, stream>>>(sbuf, batch, smax, t0);
    expsum_k<<<dim3(N_ / 256, zc), 256, 0, stream>>>(sbuf, batch, smax, esum, t0);
    poolscat_k<<<dim3(N_, zc), 256, 0, stream>>>(bufA, sbuf, esum, batch, pooled, t0);
  }

  // ----- temporal transformer -----
  build_seq_k<<<dim3(S_, B_), 256, 0, stream>>>(pooled, cls, pos, seq);
  const int M = B_ * S_;  // 1088 = 17*64
  for (int l = 0; l < L_; ++l) {
    gemm_k<0><<<dim3(3 * H_ / 64, M / 64, 1), 256, 0, stream>>>(
        seq, 0, qkvw + (long)l * H_ * 3 * H_, qkvbias + (long)l * 3 * H_, qkvbuf, 0, H_, 3 * H_);
    attn_k<<<dim3(B_, HEADS_), 256, 0, stream>>>(qkvbuf, obuf);
    gemm_k<0><<<dim3(H_ / 64, M / 64, 1), 256, 0, stream>>>(
        obuf, 0, outw + (long)l * H_ * H_, outb + (long)l * H_, qkvbuf, 0, H_, H_);
    resid_ln_k<<<dim3(M), 256, 0, stream>>>(seq, qkvbuf, l1g + (long)l * H_, l1b + (long)l * H_);
    gemm_k<1><<<dim3(DFF_ / 64, M / 64, 1), 256, 0, stream>>>(
        seq, 0, f1w + (long)l * H_ * DFF_, f1b + (long)l * DFF_, ffbuf, 0, H_, DFF_);
    gemm_k<0><<<dim3(H_ / 64, M / 64, 1), 256, 0, stream>>>(
        ffbuf, 0, f2w + (long)l * DFF_ * H_, f2b + (long)l * H_, obuf, 0, DFF_, H_);
    resid_ln_k<<<dim3(M), 256, 0, stream>>>(seq, obuf, l2g + (long)l * H_, l2b + (long)l * H_);
  }
  head_k<<<dim3(B_), 256, 0, stream>>>(seq, hw, hb, out);
}

// Round 2
// 2622.412 us; speedup vs baseline: 1.4155x; 1.4155x over previous
//
#include <hip/hip_runtime.h>
#include <math.h>

#define T_ 16
#define N_ 6400
#define E_ 65536
#define IN_ 128
#define ED_ 16
#define H_ 256
#define B_ 64
#define HEADS_ 8
#define L_ 2
#define DFF_ 2048
#define OUT_ 8
#define DH_ 32
#define S_ 17

// ---------------- utility ----------------
__global__ void zero_k(float* __restrict__ p, long n) {
  long i = (long)blockIdx.x * 256 + threadIdx.x;
  if (i < n) p[i] = 0.f;
}

// ---------------- GEMM: O[M,Nc] = A[M,K] @ W[K,Nc] + bias, epilogue ----------------
// EP: 0 none, 1 relu, 2 tanh
template <int EP>
__launch_bounds__(256) __global__
void gemm_k(const float* __restrict__ Abase, long az,
            const float* __restrict__ W, const float* __restrict__ bias,
            float* __restrict__ Obase, long oz, int K, int Nc) {
  const float* A = Abase + (long)blockIdx.z * az;
  float* O = Obase + (long)blockIdx.z * oz;
  const int n0 = blockIdx.x * 64;
  const int m0 = blockIdx.y * 64;
  const int tid = threadIdx.x;
  const int tx = tid & 15, ty = tid >> 4;
  __shared__ float As[16][64];
  __shared__ float Ws[16][64];
  float acc[4][4] = {{0.f, 0.f, 0.f, 0.f}, {0.f, 0.f, 0.f, 0.f},
                     {0.f, 0.f, 0.f, 0.f}, {0.f, 0.f, 0.f, 0.f}};
  const int ar = tid >> 2;
  const int ak = (tid & 3) << 2;
  const int wr = tid >> 4;
  const int wc = (tid & 15) << 2;
  for (int k0 = 0; k0 < K; k0 += 16) {
    const float4 av = *(const float4*)(A + (long)(m0 + ar) * K + k0 + ak);
    const float4 wv = *(const float4*)(W + (long)(k0 + wr) * Nc + n0 + wc);
    __syncthreads();
    As[ak + 0][ar] = av.x;
    As[ak + 1][ar] = av.y;
    As[ak + 2][ar] = av.z;
    As[ak + 3][ar] = av.w;
    *(float4*)(&Ws[wr][wc]) = wv;
    __syncthreads();
#pragma unroll
    for (int kk = 0; kk < 16; ++kk) {
      const float4 a4 = *(const float4*)(&As[kk][ty << 2]);
      const float4 b4 = *(const float4*)(&Ws[kk][tx << 2]);
      const float aa[4] = {a4.x, a4.y, a4.z, a4.w};
      const float bb[4] = {b4.x, b4.y, b4.z, b4.w};
#pragma unroll
      for (int i = 0; i < 4; ++i)
#pragma unroll
        for (int j = 0; j < 4; ++j) acc[i][j] = fmaf(aa[i], bb[j], acc[i][j]);
    }
  }
#pragma unroll
  for (int i = 0; i < 4; ++i) {
    const int m = m0 + (ty << 2) + i;
    float o[4];
#pragma unroll
    for (int j = 0; j < 4; ++j) {
      float v = acc[i][j];
      if (bias) v += bias[n0 + (tx << 2) + j];
      if (EP == 1) v = fmaxf(v, 0.f);
      if (EP == 2) v = tanhf(v);
      o[j] = v;
    }
    *(float4*)(O + (long)m * Nc + n0 + (tx << 2)) = make_float4(o[0], o[1], o[2], o[3]);
  }
}

// ---------------- CSR build ----------------
__global__ void deg_k(const int* __restrict__ eib, int* __restrict__ deg, int t0) {
  const int z = blockIdx.y;
  const int e = blockIdx.x * 256 + threadIdx.x;
  const int dst = eib[(long)(t0 + z) * 2 * E_ + E_ + e];
  atomicAdd(&deg[z * N_ + dst], 1);
}

// one block per day; 256 thr x 25 elems = 6400
__launch_bounds__(256) __global__
void scan_k(const int* __restrict__ deg, int* __restrict__ offs, int* __restrict__ cursor) {
  const int z = blockIdx.x, tid = threadIdx.x;
  const int* d = deg + (long)z * N_;
  const int base = tid * 25;
  int loc[25];
  int s = 0;
#pragma unroll
  for (int i = 0; i < 25; ++i) {
    loc[i] = s;
    s += d[base + i];
  }
  __shared__ int ps[256];
  ps[tid] = s;
  __syncthreads();
  for (int off = 1; off < 256; off <<= 1) {
    int v = 0;
    if (tid >= off) v = ps[tid - off];
    __syncthreads();
    if (tid >= off) ps[tid] += v;
    __syncthreads();
  }
  const int pre = (tid == 0) ? 0 : ps[tid - 1];
#pragma unroll
  for (int i = 0; i < 25; ++i) {
    const int o = pre + loc[i];
    offs[(long)z * (N_ + 1) + base + i] = o;
    cursor[(long)z * N_ + base + i] = o;
  }
  if (tid == 255) offs[(long)z * (N_ + 1) + N_] = ps[255];
}

__global__ void fill_k(const int* __restrict__ eib, int* __restrict__ cursor,
                       int* __restrict__ elist, int t0) {
  const int z = blockIdx.y;
  const int e = blockIdx.x * 256 + threadIdx.x;
  const int dst = eib[(long)(t0 + z) * 2 * E_ + E_ + e];
  const int slot = atomicAdd(&cursor[z * N_ + dst], 1);
  elist[(long)z * E_ + slot] = e;
}

// graph boundaries from sorted batch: gb[z][g] = lower_bound(batch_t, g)
__global__ void bounds_k(const int* __restrict__ batchb, int* __restrict__ gb, int t0) {
  const int z = blockIdx.x;
  const int g = threadIdx.x;
  if (g > B_) return;
  const int* bt = batchb + (long)(t0 + z) * N_;
  int lo = 0, hi = N_;
  while (lo < hi) {
    const int mid = (lo + hi) >> 1;
    if (bt[mid] < g) lo = mid + 1; else hi = mid;
  }
  gb[z * (B_ + 1) + g] = lo;
}

// ---------------- fused conv: gather + mean + root + relu + LN ----------------
__launch_bounds__(256) __global__
void conv_fused_k(const float* __restrict__ xw, const float* __restrict__ root,
                  const float* __restrict__ eab, const int* __restrict__ eib,
                  const int* __restrict__ elist, const int* __restrict__ offs,
                  const float* __restrict__ wnb, const float* __restrict__ g,
                  const float* __restrict__ bb, float* __restrict__ outh, int t0) {
  const int z = blockIdx.y;
  const int n = blockIdx.x;
  const int c = threadIdx.x;
  const int t = t0 + z;
  const int* srcp = eib + (long)t * 2 * E_;
  const float* ea = eab + (long)t * E_ * ED_;
  const int beg = offs[(long)z * (N_ + 1) + n];
  const int end = offs[(long)z * (N_ + 1) + n + 1];
  float wreg[ED_];
#pragma unroll
  for (int k = 0; k < ED_; ++k) wreg[k] = wnb[k * H_ + c];
  const float* xwz = xw + (long)z * N_ * H_;
  float v = 0.f;
  for (int j = beg; j < end; ++j) {
    const int e = elist[(long)z * E_ + j];
    const int s = srcp[e];
    float v2 = xwz[(long)s * H_ + c];
    const float4* er = (const float4*)(ea + (long)e * ED_);
    const float4 e0 = er[0], e1 = er[1], e2 = er[2], e3 = er[3];
    v2 = fmaf(e0.x, wreg[0], v2);  v2 = fmaf(e0.y, wreg[1], v2);
    v2 = fmaf(e0.z, wreg[2], v2);  v2 = fmaf(e0.w, wreg[3], v2);
    v2 = fmaf(e1.x, wreg[4], v2);  v2 = fmaf(e1.y, wreg[5], v2);
    v2 = fmaf(e1.z, wreg[6], v2);  v2 = fmaf(e1.w, wreg[7], v2);
    v2 = fmaf(e2.x, wreg[8], v2);  v2 = fmaf(e2.y, wreg[9], v2);
    v2 = fmaf(e2.z, wreg[10], v2); v2 = fmaf(e2.w, wreg[11], v2);
    v2 = fmaf(e3.x, wreg[12], v2); v2 = fmaf(e3.y, wreg[13], v2);
    v2 = fmaf(e3.z, wreg[14], v2); v2 = fmaf(e3.w, wreg[15], v2);
    v += v2;
  }
  const float cntf = fmaxf((float)(end - beg), 1.f);
  const long row = ((long)z * N_ + n) * H_;
  v = v / cntf + root[row + c];
  v = fmaxf(v, 0.f);
  __shared__ float rs[256], rq[256];
  rs[c] = v;
  rq[c] = v * v;
  __syncthreads();
  for (int s = 128; s > 0; s >>= 1) {
    if (c < s) {
      rs[c] += rs[c + s];
      rq[c] += rq[c + s];
    }
    __syncthreads();
  }
  const float mean = rs[0] * (1.f / H_);
  const float var = rq[0] * (1.f / H_) - mean * mean;
  outh[row + c] = (v - mean) * rsqrtf(var + 1e-5f) * g[c] + bb[c];
}

// ---------------- pooling ----------------
__launch_bounds__(256) __global__
void score_k(const float* __restrict__ tnh, const float* __restrict__ sw,
             const float* __restrict__ sb, float* __restrict__ sbuf) {
  const long z = blockIdx.y;
  const int n = blockIdx.x, c = threadIdx.x;
  float p = tnh[(z * N_ + n) * (long)H_ + c] * sw[c];
  __shared__ float rs[256];
  rs[c] = p;
  __syncthreads();
  for (int s = 128; s > 0; s >>= 1) {
    if (c < s) rs[c] += rs[c + s];
    __syncthreads();
  }
  if (c == 0) sbuf[z * N_ + n] = rs[0] + sb[0];
}

// fused segment-softmax pooling, one block per (graph, day). batch sorted.
__launch_bounds__(256) __global__
void pool_k(const float* __restrict__ h, const float* __restrict__ sbuf,
            const int* __restrict__ gb, float* __restrict__ pooled, int t0) {
  const int z = blockIdx.y;
  const int g = blockIdx.x;
  const int c = threadIdx.x;
  const int beg = gb[z * (B_ + 1) + g];
  const int end = gb[z * (B_ + 1) + g + 1];
  const float* sz = sbuf + (long)z * N_;
  __shared__ float red[256];
  // max
  float m = -1e30f;
  for (int i = beg + c; i < end; i += 256) m = fmaxf(m, sz[i]);
  red[c] = m;
  __syncthreads();
  for (int s = 128; s > 0; s >>= 1) {
    if (c < s) red[c] = fmaxf(red[c], red[c + s]);
    __syncthreads();
  }
  m = red[0];
  __syncthreads();
  // exp-sum
  float sum = 0.f;
  for (int i = beg + c; i < end; i += 256) sum += expf(sz[i] - m);
  red[c] = sum;
  __syncthreads();
  for (int s = 128; s > 0; s >>= 1) {
    if (c < s) red[c] += red[c + s];
    __syncthreads();
  }
  sum = red[0];
  // weighted sum over channel c
  float acc = 0.f;
  for (int i = beg; i < end; ++i) {
    const float w = expf(sz[i] - m);
    acc = fmaf(h[((long)z * N_ + i) * H_ + c], w, acc);
  }
  pooled[((long)(t0 + z) * B_ + g) * H_ + c] = (sum > 0.f) ? acc / sum : 0.f;
}

// ---------------- transformer ----------------
__global__ void build_seq_k(const float* __restrict__ pooled, const float* __restrict__ cls,
                            const float* __restrict__ pos, float* __restrict__ seq) {
  const int s = blockIdx.x, b = blockIdx.y, c = threadIdx.x;
  const float v = (s == 0) ? cls[c] : pooled[(((long)(s - 1)) * B_ + b) * H_ + c];
  seq[((long)b * S_ + s) * H_ + c] = v + pos[(long)s * H_ + c];
}

__launch_bounds__(256) __global__
void attn_k(const float* __restrict__ qkv, float* __restrict__ obuf) {
  const int b = blockIdx.x, h = blockIdx.y;
  __shared__ float qs[S_][DH_], ks[S_][DH_], vs[S_][DH_], att[S_][S_];
  const int tid = threadIdx.x;
  for (int i = tid; i < S_ * DH_; i += 256) {
    const int s = i / DH_, d = i % DH_;
    const long base = ((long)b * S_ + s) * (3 * H_) + h * DH_ + d;
    qs[s][d] = qkv[base];
    ks[s][d] = qkv[base + H_];
    vs[s][d] = qkv[base + 2 * H_];
  }
  __syncthreads();
  for (int i = tid; i < S_ * S_; i += 256) {
    const int r = i / S_, c2 = i % S_;
    float acc = 0.f;
#pragma unroll
    for (int d = 0; d < DH_; ++d) acc = fmaf(qs[r][d], ks[c2][d], acc);
    att[r][c2] = acc * 0.17677669529663687f;
  }
  __syncthreads();
  if (tid < S_) {
    float m = -1e30f;
    for (int j = 0; j < S_; ++j) m = fmaxf(m, att[tid][j]);
    float sum = 0.f;
    for (int j = 0; j < S_; ++j) {
      const float e = expf(att[tid][j] - m);
      att[tid][j] = e;
      sum += e;
    }
    const float inv = 1.f / sum;
    for (int j = 0; j < S_; ++j) att[tid][j] *= inv;
  }
  __syncthreads();
  for (int i = tid; i < S_ * DH_; i += 256) {
    const int s = i / DH_, d = i % DH_;
    float acc = 0.f;
#pragma unroll
    for (int j = 0; j < S_; ++j) acc = fmaf(att[s][j], vs[j][d], acc);
    obuf[((long)b * S_ + s) * H_ + h * DH_ + d] = acc;
  }
}

__launch_bounds__(256) __global__
void resid_ln_k(float* __restrict__ seq, const float* __restrict__ add,
                const float* __restrict__ g, const float* __restrict__ bb) {
  const int row = blockIdx.x, c = threadIdx.x;
  const float v = seq[(long)row * H_ + c] + add[(long)row * H_ + c];
  __shared__ float rs[256], rq[256];
  rs[c] = v;
  rq[c] = v * v;
  __syncthreads();
  for (int s = 128; s > 0; s >>= 1) {
    if (c < s) {
      rs[c] += rs[c + s];
      rq[c] += rq[c + s];
    }
    __syncthreads();
  }
  const float mean = rs[0] * (1.f / H_);
  const float var = rq[0] * (1.f / H_) - mean * mean;
  seq[(long)row * H_ + c] = (v - mean) * rsqrtf(var + 1e-5f) * g[c] + bb[c];
}

__launch_bounds__(256) __global__
void head_k(const float* __restrict__ seq, const float* __restrict__ hw,
            const float* __restrict__ hb, float* __restrict__ out) {
  const int b = blockIdx.x, c = threadIdx.x;
  const float x = seq[(long)b * S_ * H_ + c];
  __shared__ float rs[256];
  for (int o = 0; o < OUT_; ++o) {
    rs[c] = x * hw[c * OUT_ + o];
    __syncthreads();
    for (int s = 128; s > 0; s >>= 1) {
      if (c < s) rs[c] += rs[c + s];
      __syncthreads();
    }
    if (c == 0) {
      const float v = rs[0] + hb[o];
      out[b * OUT_ + o] = fmaxf(v, 0.f) + log1pf(expf(-fabsf(v)));
    }
    __syncthreads();
  }
}

// ---------------- launcher ----------------
extern "C" void kernel_launch(void* const* d_in, const int* in_sizes, int n_in,
                              void* d_out, int out_size, void* d_ws, size_t ws_size,
                              hipStream_t stream) {
  const float* x = (const float*)d_in[0];
  const float* ea = (const float*)d_in[1];
  const int* ei = (const int*)d_in[2];
  const int* batch = (const int*)d_in[3];
  const float* nw0 = (const float*)d_in[4];
  const float* nb0 = (const float*)d_in[5];
  const float* rw0 = (const float*)d_in[6];
  const float* rb0 = (const float*)d_in[7];
  const float* lg0 = (const float*)d_in[8];
  const float* lb0 = (const float*)d_in[9];
  const float* nw1 = (const float*)d_in[10];
  const float* nb1 = (const float*)d_in[11];
  const float* rw1 = (const float*)d_in[12];
  const float* rb1 = (const float*)d_in[13];
  const float* lg1 = (const float*)d_in[14];
  const float* lb1 = (const float*)d_in[15];
  const float* ppw = (const float*)d_in[16];
  const float* ppb = (const float*)d_in[17];
  const float* psw = (const float*)d_in[18];
  const float* psb = (const float*)d_in[19];
  const float* pos = (const float*)d_in[20];
  const float* cls = (const float*)d_in[21];
  const float* qkvw = (const float*)d_in[22];
  const float* qkvbias = (const float*)d_in[23];
  const float* outw = (const float*)d_in[24];
  const float* outb = (const float*)d_in[25];
  const float* f1w = (const float*)d_in[26];
  const float* f1b = (const float*)d_in[27];
  const float* f2w = (const float*)d_in[28];
  const float* f2b = (const float*)d_in[29];
  const float* l1g = (const float*)d_in[30];
  const float* l1b = (const float*)d_in[31];
  const float* l2g = (const float*)d_in[32];
  const float* l2b = (const float*)d_in[33];
  const float* hw = (const float*)d_in[34];
  const float* hb = (const float*)d_in[35];
  float* out = (float*)d_out;

  float* ws = (float*)d_ws;
  const long NH = (long)N_ * H_;
  const long fixedf = (long)T_ * B_ * H_ + (long)B_ * S_ * H_ + (long)B_ * S_ * 3 * H_ +
                      (long)B_ * S_ * H_ + (long)B_ * S_ * DFF_;
  const long perday = 3L * NH + N_                       // float bufs + sbuf
                      + E_ + (N_ + 1) + 2L * N_ + (B_ + 1);  // int bufs
  int DT = 16;
  while (DT > 1 && (size_t)(fixedf + (long)DT * perday) * 4 > ws_size) DT >>= 1;

  float* pooled = ws;
  float* seq = pooled + (long)T_ * B_ * H_;
  float* qkvbuf = seq + (long)B_ * S_ * H_;
  float* obuf = qkvbuf + (long)B_ * S_ * 3 * H_;
  float* ffbuf = obuf + (long)B_ * S_ * H_;
  float* bufA = ffbuf + (long)B_ * S_ * DFF_;
  float* bufR = bufA + (long)DT * NH;
  float* bufD = bufR + (long)DT * NH;
  float* sbuf = bufD + (long)DT * NH;
  int* elist = (int*)(sbuf + (long)DT * N_);
  int* offs = elist + (long)DT * E_;
  int* cursor = offs + (long)DT * (N_ + 1);
  int* deg = cursor + (long)DT * N_;
  int* gb = deg + (long)DT * N_;

  auto zero = [&](float* p, long n) {
    zero_k<<<dim3((unsigned)((n + 255) / 256)), 256, 0, stream>>>(p, n);
  };

  for (int t0 = 0; t0 < T_; t0 += DT) {
    const int zc = DT;
    // ----- CSR + graph bounds -----
    zero((float*)deg, (long)zc * N_);
    deg_k<<<dim3(E_ / 256, zc), 256, 0, stream>>>(ei, deg, t0);
    scan_k<<<dim3(zc), 256, 0, stream>>>(deg, offs, cursor);
    fill_k<<<dim3(E_ / 256, zc), 256, 0, stream>>>(ei, cursor, elist, t0);
    bounds_k<<<dim3(zc), 128, 0, stream>>>(batch, gb, t0);
    // ----- conv layer 0 -----
    gemm_k<0><<<dim3(H_ / 64, N_ / 64, zc), 256, 0, stream>>>(
        x + (long)t0 * N_ * IN_, (long)N_ * IN_, nw0, nb0, bufA, NH, IN_, H_);
    gemm_k<0><<<dim3(H_ / 64, N_ / 64, zc), 256, 0, stream>>>(
        x + (long)t0 * N_ * IN_, (long)N_ * IN_, rw0, rb0, bufR, NH, IN_, H_);
    conv_fused_k<<<dim3(N_, zc), 256, 0, stream>>>(bufA, bufR, ea, ei, elist, offs,
                                                   nw0 + (long)IN_ * H_, lg0, lb0, bufD, t0);
    // ----- conv layer 1 -----
    gemm_k<0><<<dim3(H_ / 64, N_ / 64, zc), 256, 0, stream>>>(bufD, NH, nw1, nb1, bufA, NH, H_, H_);
    gemm_k<0><<<dim3(H_ / 64, N_ / 64, zc), 256, 0, stream>>>(bufD, NH, rw1, rb1, bufR, NH, H_, H_);
    conv_fused_k<<<dim3(N_, zc), 256, 0, stream>>>(bufA, bufR, ea, ei, elist, offs,
                                                   nw1 + (long)H_ * H_, lg1, lb1, bufD, t0);
    // ----- pooling (h is in bufD) -----
    gemm_k<2><<<dim3(H_ / 64, N_ / 64, zc), 256, 0, stream>>>(bufD, NH, ppw, ppb, bufA, NH, H_, H_);
    score_k<<<dim3(N_, zc), 256, 0, stream>>>(bufA, psw, psb, sbuf);
    pool_k<<<dim3(B_, zc), 256, 0, stream>>>(bufD, sbuf, gb, pooled, t0);
  }

  // ----- temporal transformer -----
  build_seq_k<<<dim3(S_, B_), 256, 0, stream>>>(pooled, cls, pos, seq);
  const int M = B_ * S_;  // 1088
  for (int l = 0; l < L_; ++l) {
    gemm_k<0><<<dim3(3 * H_ / 64, M / 64, 1), 256, 0, stream>>>(
        seq, 0, qkvw + (long)l * H_ * 3 * H_, qkvbias + (long)l * 3 * H_, qkvbuf, 0, H_, 3 * H_);
    attn_k<<<dim3(B_, HEADS_), 256, 0, stream>>>(qkvbuf, obuf);
    gemm_k<0><<<dim3(H_ / 64, M / 64, 1), 256, 0, stream>>>(
        obuf, 0, outw + (long)l * H_ * H_, outb + (long)l * H_, qkvbuf, 0, H_, H_);
    resid_ln_k<<<dim3(M), 256, 0, stream>>>(seq, qkvbuf, l1g + (long)l * H_, l1b + (long)l * H_);
    gemm_k<1><<<dim3(DFF_ / 64, M / 64, 1), 256, 0, stream>>>(
        seq, 0, f1w + (long)l * H_ * DFF_, f1b + (long)l * DFF_, ffbuf, 0, H_, DFF_);
    gemm_k<0><<<dim3(H_ / 64, M / 64, 1), 256, 0, stream>>>(
        ffbuf, 0, f2w + (long)l * DFF_ * H_, f2b + (long)l * H_, obuf, 0, DFF_, H_);
    resid_ln_k<<<dim3(M), 256, 0, stream>>>(seq, obuf, l2g + (long)l * H_, l2b + (long)l * H_);
  }
  head_k<<<dim3(B_), 256, 0, stream>>>(seq, hw, hb, out);
}

// Round 3
// 2110.842 us; speedup vs baseline: 1.7585x; 1.2424x over previous
//
#include <hip/hip_runtime.h>
#include <math.h>

#define T_ 16
#define N_ 6400
#define E_ 65536
#define IN_ 128
#define ED_ 16
#define H_ 256
#define B_ 64
#define HEADS_ 8
#define L_ 2
#define DFF_ 2048
#define OUT_ 8
#define DH_ 32
#define S_ 17

// ---------------- utility ----------------
__global__ void zero_k(float* __restrict__ p, long n) {
  long i = (long)blockIdx.x * 256 + threadIdx.x;
  if (i < n) p[i] = 0.f;
}

// ---------------- GEMM: O[M,Nc] = A[M,K] @ W[K,Nc] + bias + addp ----------------
// EP: 0 none, 1 relu, 2 tanh
template <int EP>
__launch_bounds__(256) __global__
void gemm_k(const float* __restrict__ Abase, long az,
            const float* __restrict__ W, const float* __restrict__ bias,
            const float* __restrict__ addbase, long adz,
            float* __restrict__ Obase, long oz, int K, int Nc) {
  const float* A = Abase + (long)blockIdx.z * az;
  const float* addp = addbase ? addbase + (long)blockIdx.z * adz : (const float*)0;
  float* O = Obase + (long)blockIdx.z * oz;
  const int n0 = blockIdx.x * 64;
  const int m0 = blockIdx.y * 64;
  const int tid = threadIdx.x;
  const int tx = tid & 15, ty = tid >> 4;
  __shared__ float As[16][64];
  __shared__ float Ws[16][64];
  float acc[4][4] = {{0.f, 0.f, 0.f, 0.f}, {0.f, 0.f, 0.f, 0.f},
                     {0.f, 0.f, 0.f, 0.f}, {0.f, 0.f, 0.f, 0.f}};
  const int ar = tid >> 2;
  const int ak = (tid & 3) << 2;
  const int wr = tid >> 4;
  const int wc = (tid & 15) << 2;
  for (int k0 = 0; k0 < K; k0 += 16) {
    const float4 av = *(const float4*)(A + (long)(m0 + ar) * K + k0 + ak);
    const float4 wv = *(const float4*)(W + (long)(k0 + wr) * Nc + n0 + wc);
    __syncthreads();
    As[ak + 0][ar] = av.x;
    As[ak + 1][ar] = av.y;
    As[ak + 2][ar] = av.z;
    As[ak + 3][ar] = av.w;
    *(float4*)(&Ws[wr][wc]) = wv;
    __syncthreads();
#pragma unroll
    for (int kk = 0; kk < 16; ++kk) {
      const float4 a4 = *(const float4*)(&As[kk][ty << 2]);
      const float4 b4 = *(const float4*)(&Ws[kk][tx << 2]);
      const float aa[4] = {a4.x, a4.y, a4.z, a4.w};
      const float bb[4] = {b4.x, b4.y, b4.z, b4.w};
#pragma unroll
      for (int i = 0; i < 4; ++i)
#pragma unroll
        for (int j = 0; j < 4; ++j) acc[i][j] = fmaf(aa[i], bb[j], acc[i][j]);
    }
  }
#pragma unroll
  for (int i = 0; i < 4; ++i) {
    const int m = m0 + (ty << 2) + i;
    float o[4];
#pragma unroll
    for (int j = 0; j < 4; ++j) {
      float v = acc[i][j];
      if (bias) v += bias[n0 + (tx << 2) + j];
      if (addp) v += addp[(long)m * Nc + n0 + (tx << 2) + j];
      if (EP == 1) v = fmaxf(v, 0.f);
      if (EP == 2) v = tanhf(v);
      o[j] = v;
    }
    *(float4*)(O + (long)m * Nc + n0 + (tx << 2)) = make_float4(o[0], o[1], o[2], o[3]);
  }
}

// ---------------- CSR build ----------------
__global__ void deg_k(const int* __restrict__ eib, int* __restrict__ deg, int t0) {
  const int z = blockIdx.y;
  const int e = blockIdx.x * 256 + threadIdx.x;
  const int dst = eib[(long)(t0 + z) * 2 * E_ + E_ + e];
  atomicAdd(&deg[z * N_ + dst], 1);
}

__launch_bounds__(256) __global__
void scan_k(const int* __restrict__ deg, int* __restrict__ offs, int* __restrict__ cursor) {
  const int z = blockIdx.x, tid = threadIdx.x;
  const int* d = deg + (long)z * N_;
  const int base = tid * 25;
  int loc[25];
  int s = 0;
#pragma unroll
  for (int i = 0; i < 25; ++i) {
    loc[i] = s;
    s += d[base + i];
  }
  __shared__ int ps[256];
  ps[tid] = s;
  __syncthreads();
  for (int off = 1; off < 256; off <<= 1) {
    int v = 0;
    if (tid >= off) v = ps[tid - off];
    __syncthreads();
    if (tid >= off) ps[tid] += v;
    __syncthreads();
  }
  const int pre = (tid == 0) ? 0 : ps[tid - 1];
#pragma unroll
  for (int i = 0; i < 25; ++i) {
    const int o = pre + loc[i];
    offs[(long)z * (N_ + 1) + base + i] = o;
    cursor[(long)z * N_ + base + i] = o;
  }
  if (tid == 255) offs[(long)z * (N_ + 1) + N_] = ps[255];
}

__global__ void fill_k(const int* __restrict__ eib, int* __restrict__ cursor,
                       int* __restrict__ elist, int* __restrict__ srcs, int t0) {
  const int z = blockIdx.y;
  const int e = blockIdx.x * 256 + threadIdx.x;
  const int* base = eib + (long)(t0 + z) * 2 * E_;
  const int src = base[e];
  const int dst = base[E_ + e];
  const int slot = atomicAdd(&cursor[z * N_ + dst], 1);
  elist[(long)z * E_ + slot] = e;
  srcs[(long)z * E_ + slot] = src;
}

__global__ void bounds_k(const int* __restrict__ batchb, int* __restrict__ gb, int t0) {
  const int z = blockIdx.x;
  const int g = threadIdx.x;
  if (g > B_) return;
  const int* bt = batchb + (long)(t0 + z) * N_;
  int lo = 0, hi = N_;
  while (lo < hi) {
    const int mid = (lo + hi) >> 1;
    if (bt[mid] < g) lo = mid + 1; else hi = mid;
  }
  gb[z * (B_ + 1) + g] = lo;
}

// ---------------- per-node mean of edge attrs: eaggc[n,16] = (sum ea)/cnt ----------------
// block = 256 thr = 16 nodes x 16 channels
__launch_bounds__(256) __global__
void eagg_k(const float* __restrict__ eab, const int* __restrict__ elist,
            const int* __restrict__ offs, float* __restrict__ eaggc, int t0) {
  const int z = blockIdx.y;
  const int ln = threadIdx.x >> 4;
  const int c = threadIdx.x & 15;
  const int n = blockIdx.x * 16 + ln;
  const int beg = offs[(long)z * (N_ + 1) + n];
  const int end = offs[(long)z * (N_ + 1) + n + 1];
  const float* ea = eab + (long)(t0 + z) * E_ * ED_;
  const int* el = elist + (long)z * E_;
  float v = 0.f;
  for (int j = beg; j < end; ++j) v += ea[(long)el[j] * ED_ + c];
  eaggc[((long)z * N_ + n) * ED_ + c] = v / fmaxf((float)(end - beg), 1.f);
}

// ---------------- fused conv gather: (sum xw[src])/cnt + pre, relu, LN ----------------
// one wave per node, 4 nodes per block; lane handles 4 channels (float4)
__launch_bounds__(256) __global__
void conv_gather_k(const float* __restrict__ xw, const float* __restrict__ pre,
                   const int* __restrict__ srcs, const int* __restrict__ offs,
                   const float* __restrict__ g, const float* __restrict__ bb,
                   float* __restrict__ outh) {
  const int z = blockIdx.y;
  const int wid = threadIdx.x >> 6;
  const int lane = threadIdx.x & 63;
  const int n = blockIdx.x * 4 + wid;
  const int beg = offs[(long)z * (N_ + 1) + n];
  const int end = offs[(long)z * (N_ + 1) + n + 1];
  const int* sp = srcs + (long)z * E_;
  const float* xwz = xw + (long)z * N_ * H_;
  const int co = lane << 2;
  float4 v = make_float4(0.f, 0.f, 0.f, 0.f);
  int j = beg;
  for (; j + 1 < end; j += 2) {
    const int s0 = sp[j], s1 = sp[j + 1];
    const float4 a = *(const float4*)(xwz + (long)s0 * H_ + co);
    const float4 b2 = *(const float4*)(xwz + (long)s1 * H_ + co);
    v.x += a.x + b2.x;
    v.y += a.y + b2.y;
    v.z += a.z + b2.z;
    v.w += a.w + b2.w;
  }
  if (j < end) {
    const float4 a = *(const float4*)(xwz + (long)sp[j] * H_ + co);
    v.x += a.x;
    v.y += a.y;
    v.z += a.z;
    v.w += a.w;
  }
  const float inv = 1.f / fmaxf((float)(end - beg), 1.f);
  const long row = ((long)z * N_ + n) * H_;
  const float4 p = *(const float4*)(pre + row + co);
  const float o0 = fmaxf(fmaf(v.x, inv, p.x), 0.f);
  const float o1 = fmaxf(fmaf(v.y, inv, p.y), 0.f);
  const float o2 = fmaxf(fmaf(v.z, inv, p.z), 0.f);
  const float o3 = fmaxf(fmaf(v.w, inv, p.w), 0.f);
  float s = o0 + o1 + o2 + o3;
  float q = o0 * o0 + o1 * o1 + o2 * o2 + o3 * o3;
#pragma unroll
  for (int m = 1; m < 64; m <<= 1) {
    s += __shfl_xor(s, m, 64);
    q += __shfl_xor(q, m, 64);
  }
  const float mean = s * (1.f / H_);
  const float var = q * (1.f / H_) - mean * mean;
  const float r = rsqrtf(var + 1e-5f);
  const float4 gg = *(const float4*)(g + co);
  const float4 bv = *(const float4*)(bb + co);
  float4 o;
  o.x = (o0 - mean) * r * gg.x + bv.x;
  o.y = (o1 - mean) * r * gg.y + bv.y;
  o.z = (o2 - mean) * r * gg.z + bv.z;
  o.w = (o3 - mean) * r * gg.w + bv.w;
  *(float4*)(outh + row + co) = o;
}

// ---------------- pooling ----------------
__launch_bounds__(256) __global__
void score_k(const float* __restrict__ tnh, const float* __restrict__ sw,
             const float* __restrict__ sb, float* __restrict__ sbuf) {
  const long z = blockIdx.y;
  const int n = blockIdx.x, c = threadIdx.x;
  float p = tnh[(z * N_ + n) * (long)H_ + c] * sw[c];
  __shared__ float rs[256];
  rs[c] = p;
  __syncthreads();
  for (int s = 128; s > 0; s >>= 1) {
    if (c < s) rs[c] += rs[c + s];
    __syncthreads();
  }
  if (c == 0) sbuf[z * N_ + n] = rs[0] + sb[0];
}

__launch_bounds__(256) __global__
void pool_k(const float* __restrict__ h, const float* __restrict__ sbuf,
            const int* __restrict__ gb, float* __restrict__ pooled, int t0) {
  const int z = blockIdx.y;
  const int g = blockIdx.x;
  const int c = threadIdx.x;
  const int beg = gb[z * (B_ + 1) + g];
  const int end = gb[z * (B_ + 1) + g + 1];
  const float* sz = sbuf + (long)z * N_;
  __shared__ float red[256];
  float m = -1e30f;
  for (int i = beg + c; i < end; i += 256) m = fmaxf(m, sz[i]);
  red[c] = m;
  __syncthreads();
  for (int s = 128; s > 0; s >>= 1) {
    if (c < s) red[c] = fmaxf(red[c], red[c + s]);
    __syncthreads();
  }
  m = red[0];
  __syncthreads();
  float sum = 0.f;
  for (int i = beg + c; i < end; i += 256) sum += expf(sz[i] - m);
  red[c] = sum;
  __syncthreads();
  for (int s = 128; s > 0; s >>= 1) {
    if (c < s) red[c] += red[c + s];
    __syncthreads();
  }
  sum = red[0];
  float acc = 0.f;
  for (int i = beg; i < end; ++i) {
    const float w = expf(sz[i] - m);
    acc = fmaf(h[((long)z * N_ + i) * H_ + c], w, acc);
  }
  pooled[((long)(t0 + z) * B_ + g) * H_ + c] = (sum > 0.f) ? acc / sum : 0.f;
}

// ---------------- transformer ----------------
__global__ void build_seq_k(const float* __restrict__ pooled, const float* __restrict__ cls,
                            const float* __restrict__ pos, float* __restrict__ seq) {
  const int s = blockIdx.x, b = blockIdx.y, c = threadIdx.x;
  const float v = (s == 0) ? cls[c] : pooled[(((long)(s - 1)) * B_ + b) * H_ + c];
  seq[((long)b * S_ + s) * H_ + c] = v + pos[(long)s * H_ + c];
}

__launch_bounds__(256) __global__
void attn_k(const float* __restrict__ qkv, float* __restrict__ obuf) {
  const int b = blockIdx.x, h = blockIdx.y;
  __shared__ float qs[S_][DH_], ks[S_][DH_], vs[S_][DH_], att[S_][S_];
  const int tid = threadIdx.x;
  for (int i = tid; i < S_ * DH_; i += 256) {
    const int s = i / DH_, d = i % DH_;
    const long base = ((long)b * S_ + s) * (3 * H_) + h * DH_ + d;
    qs[s][d] = qkv[base];
    ks[s][d] = qkv[base + H_];
    vs[s][d] = qkv[base + 2 * H_];
  }
  __syncthreads();
  for (int i = tid; i < S_ * S_; i += 256) {
    const int r = i / S_, c2 = i % S_;
    float acc = 0.f;
#pragma unroll
    for (int d = 0; d < DH_; ++d) acc = fmaf(qs[r][d], ks[c2][d], acc);
    att[r][c2] = acc * 0.17677669529663687f;
  }
  __syncthreads();
  if (tid < S_) {
    float m = -1e30f;
    for (int j = 0; j < S_; ++j) m = fmaxf(m, att[tid][j]);
    float sum = 0.f;
    for (int j = 0; j < S_; ++j) {
      const float e = expf(att[tid][j] - m);
      att[tid][j] = e;
      sum += e;
    }
    const float inv = 1.f / sum;
    for (int j = 0; j < S_; ++j) att[tid][j] *= inv;
  }
  __syncthreads();
  for (int i = tid; i < S_ * DH_; i += 256) {
    const int s = i / DH_, d = i % DH_;
    float acc = 0.f;
#pragma unroll
    for (int j = 0; j < S_; ++j) acc = fmaf(att[s][j], vs[j][d], acc);
    obuf[((long)b * S_ + s) * H_ + h * DH_ + d] = acc;
  }
}

__launch_bounds__(256) __global__
void resid_ln_k(float* __restrict__ seq, const float* __restrict__ add,
                const float* __restrict__ g, const float* __restrict__ bb) {
  const int row = blockIdx.x, c = threadIdx.x;
  const float v = seq[(long)row * H_ + c] + add[(long)row * H_ + c];
  __shared__ float rs[256], rq[256];
  rs[c] = v;
  rq[c] = v * v;
  __syncthreads();
  for (int s = 128; s > 0; s >>= 1) {
    if (c < s) {
      rs[c] += rs[c + s];
      rq[c] += rq[c + s];
    }
    __syncthreads();
  }
  const float mean = rs[0] * (1.f / H_);
  const float var = rq[0] * (1.f / H_) - mean * mean;
  seq[(long)row * H_ + c] = (v - mean) * rsqrtf(var + 1e-5f) * g[c] + bb[c];
}

__launch_bounds__(256) __global__
void head_k(const float* __restrict__ seq, const float* __restrict__ hw,
            const float* __restrict__ hb, float* __restrict__ out) {
  const int b = blockIdx.x, c = threadIdx.x;
  const float x = seq[(long)b * S_ * H_ + c];
  __shared__ float rs[256];
  for (int o = 0; o < OUT_; ++o) {
    rs[c] = x * hw[c * OUT_ + o];
    __syncthreads();
    for (int s = 128; s > 0; s >>= 1) {
      if (c < s) rs[c] += rs[c + s];
      __syncthreads();
    }
    if (c == 0) {
      const float v = rs[0] + hb[o];
      out[b * OUT_ + o] = fmaxf(v, 0.f) + log1pf(expf(-fabsf(v)));
    }
    __syncthreads();
  }
}

// ---------------- launcher ----------------
extern "C" void kernel_launch(void* const* d_in, const int* in_sizes, int n_in,
                              void* d_out, int out_size, void* d_ws, size_t ws_size,
                              hipStream_t stream) {
  const float* x = (const float*)d_in[0];
  const float* ea = (const float*)d_in[1];
  const int* ei = (const int*)d_in[2];
  const int* batch = (const int*)d_in[3];
  const float* nw0 = (const float*)d_in[4];
  const float* nb0 = (const float*)d_in[5];
  const float* rw0 = (const float*)d_in[6];
  const float* rb0 = (const float*)d_in[7];
  const float* lg0 = (const float*)d_in[8];
  const float* lb0 = (const float*)d_in[9];
  const float* nw1 = (const float*)d_in[10];
  const float* nb1 = (const float*)d_in[11];
  const float* rw1 = (const float*)d_in[12];
  const float* rb1 = (const float*)d_in[13];
  const float* lg1 = (const float*)d_in[14];
  const float* lb1 = (const float*)d_in[15];
  const float* ppw = (const float*)d_in[16];
  const float* ppb = (const float*)d_in[17];
  const float* psw = (const float*)d_in[18];
  const float* psb = (const float*)d_in[19];
  const float* pos = (const float*)d_in[20];
  const float* cls = (const float*)d_in[21];
  const float* qkvw = (const float*)d_in[22];
  const float* qkvbias = (const float*)d_in[23];
  const float* outw = (const float*)d_in[24];
  const float* outb = (const float*)d_in[25];
  const float* f1w = (const float*)d_in[26];
  const float* f1b = (const float*)d_in[27];
  const float* f2w = (const float*)d_in[28];
  const float* f2b = (const float*)d_in[29];
  const float* l1g = (const float*)d_in[30];
  const float* l1b = (const float*)d_in[31];
  const float* l2g = (const float*)d_in[32];
  const float* l2b = (const float*)d_in[33];
  const float* hw = (const float*)d_in[34];
  const float* hb = (const float*)d_in[35];
  float* out = (float*)d_out;

  float* ws = (float*)d_ws;
  const long NH = (long)N_ * H_;
  const long fixedf = (long)T_ * B_ * H_ + (long)B_ * S_ * H_ + (long)B_ * S_ * 3 * H_ +
                      (long)B_ * S_ * H_ + (long)B_ * S_ * DFF_;
  const long perday = 3L * NH + N_ + (long)N_ * ED_          // float
                      + 2L * E_ + (N_ + 1) + 2L * N_ + (B_ + 1);  // int
  int DT = 16;
  while (DT > 1 && (size_t)(fixedf + (long)DT * perday) * 4 > ws_size) DT >>= 1;

  float* pooled = ws;
  float* seq = pooled + (long)T_ * B_ * H_;
  float* qkvbuf = seq + (long)B_ * S_ * H_;
  float* obuf = qkvbuf + (long)B_ * S_ * 3 * H_;
  float* ffbuf = obuf + (long)B_ * S_ * H_;
  float* bufA = ffbuf + (long)B_ * S_ * DFF_;
  float* bufR = bufA + (long)DT * NH;
  float* bufD = bufR + (long)DT * NH;
  float* sbuf = bufD + (long)DT * NH;
  float* eaggc = sbuf + (long)DT * N_;
  int* elist = (int*)(eaggc + (long)DT * N_ * ED_);
  int* srcs = elist + (long)DT * E_;
  int* offs = srcs + (long)DT * E_;
  int* cursor = offs + (long)DT * (N_ + 1);
  int* deg = cursor + (long)DT * N_;
  int* gb = deg + (long)DT * N_;

  auto zero = [&](float* p, long n) {
    zero_k<<<dim3((unsigned)((n + 255) / 256)), 256, 0, stream>>>(p, n);
  };

  for (int t0 = 0; t0 < T_; t0 += DT) {
    const int zc = DT;
    // ----- CSR + graph bounds + edge-attr aggregation -----
    zero((float*)deg, (long)zc * N_);
    deg_k<<<dim3(E_ / 256, zc), 256, 0, stream>>>(ei, deg, t0);
    scan_k<<<dim3(zc), 256, 0, stream>>>(deg, offs, cursor);
    fill_k<<<dim3(E_ / 256, zc), 256, 0, stream>>>(ei, cursor, elist, srcs, t0);
    bounds_k<<<dim3(zc), 128, 0, stream>>>(batch, gb, t0);
    eagg_k<<<dim3(N_ / 16, zc), 256, 0, stream>>>(ea, elist, offs, eaggc, t0);
    // ----- conv layer 0 -----
    gemm_k<0><<<dim3(H_ / 64, N_ / 64, zc), 256, 0, stream>>>(
        x + (long)t0 * N_ * IN_, (long)N_ * IN_, nw0, nb0, nullptr, 0, bufA, NH, IN_, H_);
    gemm_k<0><<<dim3(H_ / 64, N_ / 64, zc), 256, 0, stream>>>(
        x + (long)t0 * N_ * IN_, (long)N_ * IN_, rw0, rb0, nullptr, 0, bufR, NH, IN_, H_);
    gemm_k<0><<<dim3(H_ / 64, N_ / 64, zc), 256, 0, stream>>>(
        eaggc, (long)N_ * ED_, nw0 + (long)IN_ * H_, nullptr, bufR, NH, bufR, NH, ED_, H_);
    conv_gather_k<<<dim3(N_ / 4, zc), 256, 0, stream>>>(bufA, bufR, srcs, offs, lg0, lb0, bufD);
    // ----- conv layer 1 -----
    gemm_k<0><<<dim3(H_ / 64, N_ / 64, zc), 256, 0, stream>>>(bufD, NH, nw1, nb1, nullptr, 0,
                                                              bufA, NH, H_, H_);
    gemm_k<0><<<dim3(H_ / 64, N_ / 64, zc), 256, 0, stream>>>(bufD, NH, rw1, rb1, nullptr, 0,
                                                              bufR, NH, H_, H_);
    gemm_k<0><<<dim3(H_ / 64, N_ / 64, zc), 256, 0, stream>>>(
        eaggc, (long)N_ * ED_, nw1 + (long)H_ * H_, nullptr, bufR, NH, bufR, NH, ED_, H_);
    conv_gather_k<<<dim3(N_ / 4, zc), 256, 0, stream>>>(bufA, bufR, srcs, offs, lg1, lb1, bufD);
    // ----- pooling (h in bufD) -----
    gemm_k<2><<<dim3(H_ / 64, N_ / 64, zc), 256, 0, stream>>>(bufD, NH, ppw, ppb, nullptr, 0,
                                                              bufA, NH, H_, H_);
    score_k<<<dim3(N_, zc), 256, 0, stream>>>(bufA, psw, psb, sbuf);
    pool_k<<<dim3(B_, zc), 256, 0, stream>>>(bufD, sbuf, gb, pooled, t0);
  }

  // ----- temporal transformer -----
  build_seq_k<<<dim3(S_, B_), 256, 0, stream>>>(pooled, cls, pos, seq);
  const int M = B_ * S_;  // 1088
  for (int l = 0; l < L_; ++l) {
    gemm_k<0><<<dim3(3 * H_ / 64, M / 64, 1), 256, 0, stream>>>(
        seq, 0, qkvw + (long)l * H_ * 3 * H_, qkvbias + (long)l * 3 * H_, nullptr, 0,
        qkvbuf, 0, H_, 3 * H_);
    attn_k<<<dim3(B_, HEADS_), 256, 0, stream>>>(qkvbuf, obuf);
    gemm_k<0><<<dim3(H_ / 64, M / 64, 1), 256, 0, stream>>>(
        obuf, 0, outw + (long)l * H_ * H_, outb + (long)l * H_, nullptr, 0, qkvbuf, 0, H_, H_);
    resid_ln_k<<<dim3(M), 256, 0, stream>>>(seq, qkvbuf, l1g + (long)l * H_, l1b + (long)l * H_);
    gemm_k<1><<<dim3(DFF_ / 64, M / 64, 1), 256, 0, stream>>>(
        seq, 0, f1w + (long)l * H_ * DFF_, f1b + (long)l * DFF_, nullptr, 0, ffbuf, 0, H_, DFF_);
    gemm_k<0><<<dim3(H_ / 64, M / 64, 1), 256, 0, stream>>>(
        ffbuf, 0, f2w + (long)l * DFF_ * H_, f2b + (long)l * H_, nullptr, 0, obuf, 0, DFF_, H_);
    resid_ln_k<<<dim3(M), 256, 0, stream>>>(seq, obuf, l2g + (long)l * H_, l2b + (long)l * H_);
  }
  head_k<<<dim3(B_), 256, 0, stream>>>(seq, hw, hb, out);
}

// Round 4
// 1467.179 us; speedup vs baseline: 2.5300x; 1.4387x over previous
//
#include <hip/hip_runtime.h>
#include <math.h>

#define T_ 16
#define N_ 6400
#define E_ 65536
#define IN_ 128
#define ED_ 16
#define H_ 256
#define B_ 64
#define HEADS_ 8
#define L_ 2
#define DFF_ 2048
#define OUT_ 8
#define DH_ 32
#define S_ 17

typedef short bf16x8 __attribute__((ext_vector_type(8)));
typedef float f32x4 __attribute__((ext_vector_type(4)));

__device__ __forceinline__ unsigned short f2bf(float x) {
  unsigned u = __float_as_uint(x);
  unsigned r = (u + 0x7FFFu + ((u >> 16) & 1)) >> 16;
  return (unsigned short)r;
}
__device__ __forceinline__ float bf2f(unsigned short h) {
  return __uint_as_float(((unsigned)h) << 16);
}

// ---------------- utility ----------------
__global__ void zero_k(float* __restrict__ p, long n) {
  long i = (long)blockIdx.x * 256 + threadIdx.x;
  if (i < n) p[i] = 0.f;
}

// ---------------- MFMA GEMM (split-bf16 x3): O[M,Nc] = A[M,K]@W[K,Nc] + bias (+addp) ----
// 64x64 tile, 256 thr = 4 waves (2x2), each wave 32x32 via 2x2 16x16x32 frags.
// SPLITK==1: blockIdx.z = batch (strides az/oz). SPLITK>1: blockIdx.z = k-chunk,
// epilogue atomicAdd (O must be pre-zeroed), bias from chunk 0 only, EP must be 0.
template <int EP, int SPLITK>
__launch_bounds__(256) __global__
void gemm_mfma(const float* __restrict__ Abase, long az,
               const float* __restrict__ W, const float* __restrict__ bias,
               const float* __restrict__ addbase, long adz,
               float* __restrict__ Obase, long oz, int K, int Nc) {
  const float* A;
  const float* addp = nullptr;
  float* O;
  int kbeg, kend;
  if (SPLITK == 1) {
    A = Abase + (long)blockIdx.z * az;
    addp = addbase ? addbase + (long)blockIdx.z * adz : (const float*)0;
    O = Obase + (long)blockIdx.z * oz;
    kbeg = 0;
    kend = K;
  } else {
    A = Abase;
    O = Obase;
    const int chunk = K / SPLITK;
    kbeg = blockIdx.z * chunk;
    kend = kbeg + chunk;
  }
  const int n0 = blockIdx.x * 64;
  const int m0 = blockIdx.y * 64;
  const int tid = threadIdx.x;
  const int lane = tid & 63;
  const int wave = tid >> 6;
  const int wm = wave & 1;
  const int wn = wave >> 1;

  __shared__ unsigned short As_h[64 * 32], As_l[64 * 32];
  __shared__ unsigned short Bs_h[64 * 32], Bs_l[64 * 32];

  f32x4 acc[2][2];
#pragma unroll
  for (int i = 0; i < 2; ++i)
#pragma unroll
    for (int j = 0; j < 2; ++j) acc[i][j] = (f32x4){0.f, 0.f, 0.f, 0.f};

  // A staging indices: row = tid>>2 (0..63), kq = (tid&3)*8
  const int a_row = tid >> 2;
  const int a_kq = (tid & 3) << 3;
  // W staging indices: k-pair k2 = tid&15 (k = 2*k2, 2*k2+1), nq = (tid>>4)*4
  const int w_k2 = tid & 15;
  const int w_nq = (tid >> 4) << 2;

  const int a_quad = (lane >> 4) << 3;  // k offset 0,8,16,24
  const int a_r15 = lane & 15;

  for (int k0 = kbeg; k0 < kend; k0 += 32) {
    const float4 av0 = *(const float4*)(A + (long)(m0 + a_row) * K + k0 + a_kq);
    const float4 av1 = *(const float4*)(A + (long)(m0 + a_row) * K + k0 + a_kq + 4);
    const float4 w0 = *(const float4*)(W + (long)(k0 + 2 * w_k2) * Nc + n0 + w_nq);
    const float4 w1 = *(const float4*)(W + (long)(k0 + 2 * w_k2 + 1) * Nc + n0 + w_nq);
    __syncthreads();
    {
      const float a8[8] = {av0.x, av0.y, av0.z, av0.w, av1.x, av1.y, av1.z, av1.w};
      unsigned short h8[8], l8[8];
#pragma unroll
      for (int j = 0; j < 8; ++j) {
        h8[j] = f2bf(a8[j]);
        l8[j] = f2bf(a8[j] - bf2f(h8[j]));
      }
      const int base = a_row * 32 + a_kq;
      *(ushort4*)&As_h[base] = make_ushort4(h8[0], h8[1], h8[2], h8[3]);
      *(ushort4*)&As_h[base + 4] = make_ushort4(h8[4], h8[5], h8[6], h8[7]);
      *(ushort4*)&As_l[base] = make_ushort4(l8[0], l8[1], l8[2], l8[3]);
      *(ushort4*)&As_l[base + 4] = make_ushort4(l8[4], l8[5], l8[6], l8[7]);
    }
    {
      const float r0[4] = {w0.x, w0.y, w0.z, w0.w};
      const float r1[4] = {w1.x, w1.y, w1.z, w1.w};
#pragma unroll
      for (int j = 0; j < 4; ++j) {
        const unsigned short h0 = f2bf(r0[j]);
        const unsigned short l0 = f2bf(r0[j] - bf2f(h0));
        const unsigned short h1 = f2bf(r1[j]);
        const unsigned short l1 = f2bf(r1[j] - bf2f(h1));
        const int base = (w_nq + j) * 32 + 2 * w_k2;
        *(unsigned*)&Bs_h[base] = ((unsigned)h1 << 16) | h0;
        *(unsigned*)&Bs_l[base] = ((unsigned)l1 << 16) | l0;
      }
    }
    __syncthreads();
    bf16x8 ah[2], al[2], bh[2], bl[2];
#pragma unroll
    for (int i = 0; i < 2; ++i) {
      const int aoff = (wm * 32 + i * 16 + a_r15) * 32 + a_quad;
      ah[i] = *(const bf16x8*)&As_h[aoff];
      al[i] = *(const bf16x8*)&As_l[aoff];
      const int boff = (wn * 32 + i * 16 + a_r15) * 32 + a_quad;
      bh[i] = *(const bf16x8*)&Bs_h[boff];
      bl[i] = *(const bf16x8*)&Bs_l[boff];
    }
#pragma unroll
    for (int i = 0; i < 2; ++i)
#pragma unroll
      for (int j = 0; j < 2; ++j) {
        acc[i][j] = __builtin_amdgcn_mfma_f32_16x16x32_bf16(ah[i], bh[j], acc[i][j], 0, 0, 0);
        acc[i][j] = __builtin_amdgcn_mfma_f32_16x16x32_bf16(ah[i], bl[j], acc[i][j], 0, 0, 0);
        acc[i][j] = __builtin_amdgcn_mfma_f32_16x16x32_bf16(al[i], bh[j], acc[i][j], 0, 0, 0);
      }
  }

  const int quad4 = (lane >> 4) << 2;
#pragma unroll
  for (int i = 0; i < 2; ++i) {
#pragma unroll
    for (int j = 0; j < 2; ++j) {
      const int col = n0 + wn * 32 + j * 16 + (lane & 15);
      const int rbase = m0 + wm * 32 + i * 16 + quad4;
      const float bv = bias ? bias[col] : 0.f;
#pragma unroll
      for (int r = 0; r < 4; ++r) {
        float v = acc[i][j][r];
        if (SPLITK == 1) {
          v += bv;
          if (addp) v += addp[(long)(rbase + r) * Nc + col];
          if (EP == 1) v = fmaxf(v, 0.f);
          if (EP == 2) v = tanhf(v);
          O[(long)(rbase + r) * Nc + col] = v;
        } else {
          if (blockIdx.z == 0) v += bv;
          atomicAdd(&O[(long)(rbase + r) * Nc + col], v);
        }
      }
    }
  }
}

// ---------------- fp32 GEMM (kept for K=16 eagg): O = A@W + bias + addp ----------------
template <int EP>
__launch_bounds__(256) __global__
void gemm_k(const float* __restrict__ Abase, long az,
            const float* __restrict__ W, const float* __restrict__ bias,
            const float* __restrict__ addbase, long adz,
            float* __restrict__ Obase, long oz, int K, int Nc) {
  const float* A = Abase + (long)blockIdx.z * az;
  const float* addp = addbase ? addbase + (long)blockIdx.z * adz : (const float*)0;
  float* O = Obase + (long)blockIdx.z * oz;
  const int n0 = blockIdx.x * 64;
  const int m0 = blockIdx.y * 64;
  const int tid = threadIdx.x;
  const int tx = tid & 15, ty = tid >> 4;
  __shared__ float As[16][64];
  __shared__ float Ws[16][64];
  float acc[4][4] = {{0.f, 0.f, 0.f, 0.f}, {0.f, 0.f, 0.f, 0.f},
                     {0.f, 0.f, 0.f, 0.f}, {0.f, 0.f, 0.f, 0.f}};
  const int ar = tid >> 2;
  const int ak = (tid & 3) << 2;
  const int wr = tid >> 4;
  const int wc = (tid & 15) << 2;
  for (int k0 = 0; k0 < K; k0 += 16) {
    const float4 av = *(const float4*)(A + (long)(m0 + ar) * K + k0 + ak);
    const float4 wv = *(const float4*)(W + (long)(k0 + wr) * Nc + n0 + wc);
    __syncthreads();
    As[ak + 0][ar] = av.x;
    As[ak + 1][ar] = av.y;
    As[ak + 2][ar] = av.z;
    As[ak + 3][ar] = av.w;
    *(float4*)(&Ws[wr][wc]) = wv;
    __syncthreads();
#pragma unroll
    for (int kk = 0; kk < 16; ++kk) {
      const float4 a4 = *(const float4*)(&As[kk][ty << 2]);
      const float4 b4 = *(const float4*)(&Ws[kk][tx << 2]);
      const float aa[4] = {a4.x, a4.y, a4.z, a4.w};
      const float bb[4] = {b4.x, b4.y, b4.z, b4.w};
#pragma unroll
      for (int i = 0; i < 4; ++i)
#pragma unroll
        for (int j = 0; j < 4; ++j) acc[i][j] = fmaf(aa[i], bb[j], acc[i][j]);
    }
  }
#pragma unroll
  for (int i = 0; i < 4; ++i) {
    const int m = m0 + (ty << 2) + i;
    float o[4];
#pragma unroll
    for (int j = 0; j < 4; ++j) {
      float v = acc[i][j];
      if (bias) v += bias[n0 + (tx << 2) + j];
      if (addp) v += addp[(long)m * Nc + n0 + (tx << 2) + j];
      if (EP == 1) v = fmaxf(v, 0.f);
      if (EP == 2) v = tanhf(v);
      o[j] = v;
    }
    *(float4*)(O + (long)m * Nc + n0 + (tx << 2)) = make_float4(o[0], o[1], o[2], o[3]);
  }
}

// ---------------- CSR build ----------------
__global__ void deg_k(const int* __restrict__ eib, int* __restrict__ deg, int t0) {
  const int z = blockIdx.y;
  const int e = blockIdx.x * 256 + threadIdx.x;
  const int dst = eib[(long)(t0 + z) * 2 * E_ + E_ + e];
  atomicAdd(&deg[z * N_ + dst], 1);
}

__launch_bounds__(256) __global__
void scan_k(const int* __restrict__ deg, int* __restrict__ offs, int* __restrict__ cursor) {
  const int z = blockIdx.x, tid = threadIdx.x;
  const int* d = deg + (long)z * N_;
  const int base = tid * 25;
  int loc[25];
  int s = 0;
#pragma unroll
  for (int i = 0; i < 25; ++i) {
    loc[i] = s;
    s += d[base + i];
  }
  __shared__ int ps[256];
  ps[tid] = s;
  __syncthreads();
  for (int off = 1; off < 256; off <<= 1) {
    int v = 0;
    if (tid >= off) v = ps[tid - off];
    __syncthreads();
    if (tid >= off) ps[tid] += v;
    __syncthreads();
  }
  const int pre = (tid == 0) ? 0 : ps[tid - 1];
#pragma unroll
  for (int i = 0; i < 25; ++i) {
    const int o = pre + loc[i];
    offs[(long)z * (N_ + 1) + base + i] = o;
    cursor[(long)z * N_ + base + i] = o;
  }
  if (tid == 255) offs[(long)z * (N_ + 1) + N_] = ps[255];
}

__global__ void fill_k(const int* __restrict__ eib, int* __restrict__ cursor,
                       int* __restrict__ elist, int* __restrict__ srcs, int t0) {
  const int z = blockIdx.y;
  const int e = blockIdx.x * 256 + threadIdx.x;
  const int* base = eib + (long)(t0 + z) * 2 * E_;
  const int src = base[e];
  const int dst = base[E_ + e];
  const int slot = atomicAdd(&cursor[z * N_ + dst], 1);
  elist[(long)z * E_ + slot] = e;
  srcs[(long)z * E_ + slot] = src;
}

__global__ void bounds_k(const int* __restrict__ batchb, int* __restrict__ gb, int t0) {
  const int z = blockIdx.x;
  const int g = threadIdx.x;
  if (g > B_) return;
  const int* bt = batchb + (long)(t0 + z) * N_;
  int lo = 0, hi = N_;
  while (lo < hi) {
    const int mid = (lo + hi) >> 1;
    if (bt[mid] < g) lo = mid + 1; else hi = mid;
  }
  gb[z * (B_ + 1) + g] = lo;
}

// ---------------- per-node mean of edge attrs ----------------
__launch_bounds__(256) __global__
void eagg_k(const float* __restrict__ eab, const int* __restrict__ elist,
            const int* __restrict__ offs, float* __restrict__ eaggc, int t0) {
  const int z = blockIdx.y;
  const int ln = threadIdx.x >> 4;
  const int c = threadIdx.x & 15;
  const int n = blockIdx.x * 16 + ln;
  const int beg = offs[(long)z * (N_ + 1) + n];
  const int end = offs[(long)z * (N_ + 1) + n + 1];
  const float* ea = eab + (long)(t0 + z) * E_ * ED_;
  const int* el = elist + (long)z * E_;
  float v = 0.f;
  for (int j = beg; j < end; ++j) v += ea[(long)el[j] * ED_ + c];
  eaggc[((long)z * N_ + n) * ED_ + c] = v / fmaxf((float)(end - beg), 1.f);
}

// ---------------- fused conv gather ----------------
__launch_bounds__(256) __global__
void conv_gather_k(const float* __restrict__ xw, const float* __restrict__ pre,
                   const int* __restrict__ srcs, const int* __restrict__ offs,
                   const float* __restrict__ g, const float* __restrict__ bb,
                   float* __restrict__ outh) {
  const int z = blockIdx.y;
  const int wid = threadIdx.x >> 6;
  const int lane = threadIdx.x & 63;
  const int n = blockIdx.x * 4 + wid;
  const int beg = offs[(long)z * (N_ + 1) + n];
  const int end = offs[(long)z * (N_ + 1) + n + 1];
  const int* sp = srcs + (long)z * E_;
  const float* xwz = xw + (long)z * N_ * H_;
  const int co = lane << 2;
  float4 v = make_float4(0.f, 0.f, 0.f, 0.f);
  int j = beg;
  for (; j + 1 < end; j += 2) {
    const int s0 = sp[j], s1 = sp[j + 1];
    const float4 a = *(const float4*)(xwz + (long)s0 * H_ + co);
    const float4 b2 = *(const float4*)(xwz + (long)s1 * H_ + co);
    v.x += a.x + b2.x;
    v.y += a.y + b2.y;
    v.z += a.z + b2.z;
    v.w += a.w + b2.w;
  }
  if (j < end) {
    const float4 a = *(const float4*)(xwz + (long)sp[j] * H_ + co);
    v.x += a.x;
    v.y += a.y;
    v.z += a.z;
    v.w += a.w;
  }
  const float inv = 1.f / fmaxf((float)(end - beg), 1.f);
  const long row = ((long)z * N_ + n) * H_;
  const float4 p = *(const float4*)(pre + row + co);
  const float o0 = fmaxf(fmaf(v.x, inv, p.x), 0.f);
  const float o1 = fmaxf(fmaf(v.y, inv, p.y), 0.f);
  const float o2 = fmaxf(fmaf(v.z, inv, p.z), 0.f);
  const float o3 = fmaxf(fmaf(v.w, inv, p.w), 0.f);
  float s = o0 + o1 + o2 + o3;
  float q = o0 * o0 + o1 * o1 + o2 * o2 + o3 * o3;
#pragma unroll
  for (int m = 1; m < 64; m <<= 1) {
    s += __shfl_xor(s, m, 64);
    q += __shfl_xor(q, m, 64);
  }
  const float mean = s * (1.f / H_);
  const float var = q * (1.f / H_) - mean * mean;
  const float r = rsqrtf(var + 1e-5f);
  const float4 gg = *(const float4*)(g + co);
  const float4 bv = *(const float4*)(bb + co);
  float4 o;
  o.x = (o0 - mean) * r * gg.x + bv.x;
  o.y = (o1 - mean) * r * gg.y + bv.y;
  o.z = (o2 - mean) * r * gg.z + bv.z;
  o.w = (o3 - mean) * r * gg.w + bv.w;
  *(float4*)(outh + row + co) = o;
}

// ---------------- pooling ----------------
__launch_bounds__(256) __global__
void score_k(const float* __restrict__ tnh, const float* __restrict__ sw,
             const float* __restrict__ sb, float* __restrict__ sbuf) {
  const long z = blockIdx.y;
  const int n = blockIdx.x, c = threadIdx.x;
  float p = tnh[(z * N_ + n) * (long)H_ + c] * sw[c];
  __shared__ float rs[256];
  rs[c] = p;
  __syncthreads();
  for (int s = 128; s > 0; s >>= 1) {
    if (c < s) rs[c] += rs[c + s];
    __syncthreads();
  }
  if (c == 0) sbuf[z * N_ + n] = rs[0] + sb[0];
}

__launch_bounds__(256) __global__
void pool_k(const float* __restrict__ h, const float* __restrict__ sbuf,
            const int* __restrict__ gb, float* __restrict__ pooled, int t0) {
  const int z = blockIdx.y;
  const int g = blockIdx.x;
  const int c = threadIdx.x;
  const int beg = gb[z * (B_ + 1) + g];
  const int end = gb[z * (B_ + 1) + g + 1];
  const float* sz = sbuf + (long)z * N_;
  __shared__ float red[256];
  float m = -1e30f;
  for (int i = beg + c; i < end; i += 256) m = fmaxf(m, sz[i]);
  red[c] = m;
  __syncthreads();
  for (int s = 128; s > 0; s >>= 1) {
    if (c < s) red[c] = fmaxf(red[c], red[c + s]);
    __syncthreads();
  }
  m = red[0];
  __syncthreads();
  float sum = 0.f;
  for (int i = beg + c; i < end; i += 256) sum += expf(sz[i] - m);
  red[c] = sum;
  __syncthreads();
  for (int s = 128; s > 0; s >>= 1) {
    if (c < s) red[c] += red[c + s];
    __syncthreads();
  }
  sum = red[0];
  float acc = 0.f;
  for (int i = beg; i < end; ++i) {
    const float w = expf(sz[i] - m);
    acc = fmaf(h[((long)z * N_ + i) * H_ + c], w, acc);
  }
  pooled[((long)(t0 + z) * B_ + g) * H_ + c] = (sum > 0.f) ? acc / sum : 0.f;
}

// ---------------- transformer ----------------
__global__ void build_seq_k(const float* __restrict__ pooled, const float* __restrict__ cls,
                            const float* __restrict__ pos, float* __restrict__ seq) {
  const int s = blockIdx.x, b = blockIdx.y, c = threadIdx.x;
  const float v = (s == 0) ? cls[c] : pooled[(((long)(s - 1)) * B_ + b) * H_ + c];
  seq[((long)b * S_ + s) * H_ + c] = v + pos[(long)s * H_ + c];
}

__launch_bounds__(256) __global__
void attn_k(const float* __restrict__ qkv, float* __restrict__ obuf) {
  const int b = blockIdx.x, h = blockIdx.y;
  __shared__ float qs[S_][DH_], ks[S_][DH_], vs[S_][DH_], att[S_][S_];
  const int tid = threadIdx.x;
  for (int i = tid; i < S_ * DH_; i += 256) {
    const int s = i / DH_, d = i % DH_;
    const long base = ((long)b * S_ + s) * (3 * H_) + h * DH_ + d;
    qs[s][d] = qkv[base];
    ks[s][d] = qkv[base + H_];
    vs[s][d] = qkv[base + 2 * H_];
  }
  __syncthreads();
  for (int i = tid; i < S_ * S_; i += 256) {
    const int r = i / S_, c2 = i % S_;
    float acc = 0.f;
#pragma unroll
    for (int d = 0; d < DH_; ++d) acc = fmaf(qs[r][d], ks[c2][d], acc);
    att[r][c2] = acc * 0.17677669529663687f;
  }
  __syncthreads();
  if (tid < S_) {
    float m = -1e30f;
    for (int j = 0; j < S_; ++j) m = fmaxf(m, att[tid][j]);
    float sum = 0.f;
    for (int j = 0; j < S_; ++j) {
      const float e = expf(att[tid][j] - m);
      att[tid][j] = e;
      sum += e;
    }
    const float inv = 1.f / sum;
    for (int j = 0; j < S_; ++j) att[tid][j] *= inv;
  }
  __syncthreads();
  for (int i = tid; i < S_ * DH_; i += 256) {
    const int s = i / DH_, d = i % DH_;
    float acc = 0.f;
#pragma unroll
    for (int j = 0; j < S_; ++j) acc = fmaf(att[s][j], vs[j][d], acc);
    obuf[((long)b * S_ + s) * H_ + h * DH_ + d] = acc;
  }
}

__launch_bounds__(256) __global__
void resid_ln_k(float* __restrict__ seq, const float* __restrict__ add,
                const float* __restrict__ g, const float* __restrict__ bb) {
  const int row = blockIdx.x, c = threadIdx.x;
  const float v = seq[(long)row * H_ + c] + add[(long)row * H_ + c];
  __shared__ float rs[256], rq[256];
  rs[c] = v;
  rq[c] = v * v;
  __syncthreads();
  for (int s = 128; s > 0; s >>= 1) {
    if (c < s) {
      rs[c] += rs[c + s];
      rq[c] += rq[c + s];
    }
    __syncthreads();
  }
  const float mean = rs[0] * (1.f / H_);
  const float var = rq[0] * (1.f / H_) - mean * mean;
  seq[(long)row * H_ + c] = (v - mean) * rsqrtf(var + 1e-5f) * g[c] + bb[c];
}

__launch_bounds__(256) __global__
void head_k(const float* __restrict__ seq, const float* __restrict__ hw,
            const float* __restrict__ hb, float* __restrict__ out) {
  const int b = blockIdx.x, c = threadIdx.x;
  const float x = seq[(long)b * S_ * H_ + c];
  __shared__ float rs[256];
  for (int o = 0; o < OUT_; ++o) {
    rs[c] = x * hw[c * OUT_ + o];
    __syncthreads();
    for (int s = 128; s > 0; s >>= 1) {
      if (c < s) rs[c] += rs[c + s];
      __syncthreads();
    }
    if (c == 0) {
      const float v = rs[0] + hb[o];
      out[b * OUT_ + o] = fmaxf(v, 0.f) + log1pf(expf(-fabsf(v)));
    }
    __syncthreads();
  }
}

// ---------------- launcher ----------------
extern "C" void kernel_launch(void* const* d_in, const int* in_sizes, int n_in,
                              void* d_out, int out_size, void* d_ws, size_t ws_size,
                              hipStream_t stream) {
  const float* x = (const float*)d_in[0];
  const float* ea = (const float*)d_in[1];
  const int* ei = (const int*)d_in[2];
  const int* batch = (const int*)d_in[3];
  const float* nw0 = (const float*)d_in[4];
  const float* nb0 = (const float*)d_in[5];
  const float* rw0 = (const float*)d_in[6];
  const float* rb0 = (const float*)d_in[7];
  const float* lg0 = (const float*)d_in[8];
  const float* lb0 = (const float*)d_in[9];
  const float* nw1 = (const float*)d_in[10];
  const float* nb1 = (const float*)d_in[11];
  const float* rw1 = (const float*)d_in[12];
  const float* rb1 = (const float*)d_in[13];
  const float* lg1 = (const float*)d_in[14];
  const float* lb1 = (const float*)d_in[15];
  const float* ppw = (const float*)d_in[16];
  const float* ppb = (const float*)d_in[17];
  const float* psw = (const float*)d_in[18];
  const float* psb = (const float*)d_in[19];
  const float* pos = (const float*)d_in[20];
  const float* cls = (const float*)d_in[21];
  const float* qkvw = (const float*)d_in[22];
  const float* qkvbias = (const float*)d_in[23];
  const float* outw = (const float*)d_in[24];
  const float* outb = (const float*)d_in[25];
  const float* f1w = (const float*)d_in[26];
  const float* f1b = (const float*)d_in[27];
  const float* f2w = (const float*)d_in[28];
  const float* f2b = (const float*)d_in[29];
  const float* l1g = (const float*)d_in[30];
  const float* l1b = (const float*)d_in[31];
  const float* l2g = (const float*)d_in[32];
  const float* l2b = (const float*)d_in[33];
  const float* hw = (const float*)d_in[34];
  const float* hb = (const float*)d_in[35];
  float* out = (float*)d_out;

  float* ws = (float*)d_ws;
  const long NH = (long)N_ * H_;
  const long fixedf = (long)T_ * B_ * H_ + (long)B_ * S_ * H_ + (long)B_ * S_ * 3 * H_ +
                      (long)B_ * S_ * H_ + (long)B_ * S_ * DFF_;
  const long perday = 3L * NH + N_ + (long)N_ * ED_
                      + 2L * E_ + (N_ + 1) + 2L * N_ + (B_ + 1);
  int DT = 16;
  while (DT > 1 && (size_t)(fixedf + (long)DT * perday) * 4 > ws_size) DT >>= 1;

  float* pooled = ws;
  float* seq = pooled + (long)T_ * B_ * H_;
  float* qkvbuf = seq + (long)B_ * S_ * H_;
  float* obuf = qkvbuf + (long)B_ * S_ * 3 * H_;
  float* ffbuf = obuf + (long)B_ * S_ * H_;
  float* bufA = ffbuf + (long)B_ * S_ * DFF_;
  float* bufR = bufA + (long)DT * NH;
  float* bufD = bufR + (long)DT * NH;
  float* sbuf = bufD + (long)DT * NH;
  float* eaggc = sbuf + (long)DT * N_;
  int* elist = (int*)(eaggc + (long)DT * N_ * ED_);
  int* srcs = elist + (long)DT * E_;
  int* offs = srcs + (long)DT * E_;
  int* cursor = offs + (long)DT * (N_ + 1);
  int* deg = cursor + (long)DT * N_;
  int* gb = deg + (long)DT * N_;

  auto zero = [&](float* p, long n) {
    zero_k<<<dim3((unsigned)((n + 255) / 256)), 256, 0, stream>>>(p, n);
  };

  for (int t0 = 0; t0 < T_; t0 += DT) {
    const int zc = DT;
    // ----- CSR + graph bounds + edge-attr aggregation -----
    zero((float*)deg, (long)zc * N_);
    deg_k<<<dim3(E_ / 256, zc), 256, 0, stream>>>(ei, deg, t0);
    scan_k<<<dim3(zc), 256, 0, stream>>>(deg, offs, cursor);
    fill_k<<<dim3(E_ / 256, zc), 256, 0, stream>>>(ei, cursor, elist, srcs, t0);
    bounds_k<<<dim3(zc), 128, 0, stream>>>(batch, gb, t0);
    eagg_k<<<dim3(N_ / 16, zc), 256, 0, stream>>>(ea, elist, offs, eaggc, t0);
    // ----- conv layer 0 -----
    gemm_mfma<0, 1><<<dim3(H_ / 64, N_ / 64, zc), 256, 0, stream>>>(
        x + (long)t0 * N_ * IN_, (long)N_ * IN_, nw0, nb0, nullptr, 0, bufA, NH, IN_, H_);
    gemm_mfma<0, 1><<<dim3(H_ / 64, N_ / 64, zc), 256, 0, stream>>>(
        x + (long)t0 * N_ * IN_, (long)N_ * IN_, rw0, rb0, nullptr, 0, bufR, NH, IN_, H_);
    gemm_k<0><<<dim3(H_ / 64, N_ / 64, zc), 256, 0, stream>>>(
        eaggc, (long)N_ * ED_, nw0 + (long)IN_ * H_, nullptr, bufR, NH, bufR, NH, ED_, H_);
    conv_gather_k<<<dim3(N_ / 4, zc), 256, 0, stream>>>(bufA, bufR, srcs, offs, lg0, lb0, bufD);
    // ----- conv layer 1 -----
    gemm_mfma<0, 1><<<dim3(H_ / 64, N_ / 64, zc), 256, 0, stream>>>(
        bufD, NH, nw1, nb1, nullptr, 0, bufA, NH, H_, H_);
    gemm_mfma<0, 1><<<dim3(H_ / 64, N_ / 64, zc), 256, 0, stream>>>(
        bufD, NH, rw1, rb1, nullptr, 0, bufR, NH, H_, H_);
    gemm_k<0><<<dim3(H_ / 64, N_ / 64, zc), 256, 0, stream>>>(
        eaggc, (long)N_ * ED_, nw1 + (long)H_ * H_, nullptr, bufR, NH, bufR, NH, ED_, H_);
    conv_gather_k<<<dim3(N_ / 4, zc), 256, 0, stream>>>(bufA, bufR, srcs, offs, lg1, lb1, bufD);
    // ----- pooling (h in bufD) -----
    gemm_mfma<2, 1><<<dim3(H_ / 64, N_ / 64, zc), 256, 0, stream>>>(
        bufD, NH, ppw, ppb, nullptr, 0, bufA, NH, H_, H_);
    score_k<<<dim3(N_, zc), 256, 0, stream>>>(bufA, psw, psb, sbuf);
    pool_k<<<dim3(B_, zc), 256, 0, stream>>>(bufD, sbuf, gb, pooled, t0);
  }

  // ----- temporal transformer -----
  build_seq_k<<<dim3(S_, B_), 256, 0, stream>>>(pooled, cls, pos, seq);
  const int M = B_ * S_;  // 1088
  for (int l = 0; l < L_; ++l) {
    gemm_mfma<0, 1><<<dim3(3 * H_ / 64, M / 64, 1), 256, 0, stream>>>(
        seq, 0, qkvw + (long)l * H_ * 3 * H_, qkvbias + (long)l * 3 * H_, nullptr, 0,
        qkvbuf, 0, H_, 3 * H_);
    attn_k<<<dim3(B_, HEADS_), 256, 0, stream>>>(qkvbuf, obuf);
    gemm_mfma<0, 1><<<dim3(H_ / 64, M / 64, 1), 256, 0, stream>>>(
        obuf, 0, outw + (long)l * H_ * H_, outb + (long)l * H_, nullptr, 0, qkvbuf, 0, H_, H_);
    resid_ln_k<<<dim3(M), 256, 0, stream>>>(seq, qkvbuf, l1g + (long)l * H_, l1b + (long)l * H_);
    gemm_mfma<1, 1><<<dim3(DFF_ / 64, M / 64, 1), 256, 0, stream>>>(
        seq, 0, f1w + (long)l * H_ * DFF_, f1b + (long)l * DFF_, nullptr, 0, ffbuf, 0, H_, DFF_);
    // ff2 with split-K=8: zero obuf then accumulate
    zero(obuf, (long)M * H_);
    gemm_mfma<0, 8><<<dim3(H_ / 64, M / 64, 8), 256, 0, stream>>>(
        ffbuf, 0, f2w + (long)l * DFF_ * H_, f2b + (long)l * H_, nullptr, 0, obuf, 0, DFF_, H_);
    resid_ln_k<<<dim3(M), 256, 0, stream>>>(seq, obuf, l2g + (long)l * H_, l2b + (long)l * H_);
  }
  head_k<<<dim3(B_), 256, 0, stream>>>(seq, hw, hb, out);
}

// Round 5
// 1354.757 us; speedup vs baseline: 2.7400x; 1.0830x over previous
//
#include <hip/hip_runtime.h>
#include <math.h>

#define T_ 16
#define N_ 6400
#define E_ 65536
#define IN_ 128
#define ED_ 16
#define H_ 256
#define B_ 64
#define HEADS_ 8
#define L_ 2
#define DFF_ 2048
#define OUT_ 8
#define DH_ 32
#define S_ 17
#define M_TX (B_ * S_)  // 1088

typedef unsigned short u16;
typedef short bf16x8 __attribute__((ext_vector_type(8)));
typedef float f32x4 __attribute__((ext_vector_type(4)));

__device__ __forceinline__ u16 f2bf(float x) {
  unsigned u = __float_as_uint(x);
  unsigned r = (u + 0x7FFFu + ((u >> 16) & 1)) >> 16;
  return (u16)r;
}
__device__ __forceinline__ float bf2f(u16 h) {
  return __uint_as_float(((unsigned)h) << 16);
}

// ---------------- utility ----------------
__global__ void zero_k(float* __restrict__ p, long n) {
  long i = (long)blockIdx.x * 256 + threadIdx.x;
  if (i < n) p[i] = 0.f;
}

// split fp32 -> bf16 hi/lo planes
__global__ void split_k(const float* __restrict__ in, u16* __restrict__ h,
                        u16* __restrict__ l, long n) {
  long i = (long)blockIdx.x * 256 + threadIdx.x;
  if (i < n) {
    const float v = in[i];
    const u16 hi = f2bf(v);
    h[i] = hi;
    l[i] = f2bf(v - bf2f(hi));
  }
}

// transpose+split weight W[K][Nc] (fp32) -> Th/Tl[(row_off+n)*ldk + k] (bf16)
__launch_bounds__(256) __global__
void wconv_k(const float* __restrict__ W, int K, int Nc, u16* __restrict__ Th,
             u16* __restrict__ Tl, int row_off, int ldk) {
  __shared__ float s[16][17];
  const int kt = blockIdx.y * 16, nt = blockIdx.x * 16;
  const int a = threadIdx.x >> 4, b2 = threadIdx.x & 15;
  s[a][b2] = W[(long)(kt + a) * Nc + nt + b2];
  __syncthreads();
  const float v = s[b2][a];  // k = kt+b2, n = nt+a
  const u16 hi = f2bf(v);
  const long o = (long)(row_off + nt + a) * ldk + kt + b2;
  Th[o] = hi;
  Tl[o] = f2bf(v - bf2f(hi));
}

__global__ void biascat_k(const float* __restrict__ b1, const float* __restrict__ b2,
                          float* __restrict__ o) {
  const int i = threadIdx.x;
  o[i] = (i < 256) ? b1[i] : b2[i - 256];
}

// ---------------- MFMA GEMM (pre-split bf16 x3): O[M,Nc] = A@W ----------------
// A planes [M][K] row-major; W planes pre-transposed [Nc][K].
// 64x128 tile, 256 thr = 4 waves (2 row-halves x 2 col-halves), wave = 32x64.
// SPLITK==1: blockIdx.z = batch (strides az/oz elements). SPLITK>1: z = k-chunk,
// atomicAdd into pre-zeroed O, bias applied by chunk 0 only, EP/OUTBF must be 0.
template <int EP, int SPLITK, int OUTBF>
__launch_bounds__(256) __global__
void gemm_bf(const u16* __restrict__ Ahb, const u16* __restrict__ Alb, long az,
             const u16* __restrict__ Wth, const u16* __restrict__ Wtl,
             const float* __restrict__ bias,
             float* __restrict__ Ob, u16* __restrict__ Ohb, u16* __restrict__ Olb,
             long oz, int K, int Nc, int ldo) {
  const u16 *Ah, *Al;
  float* O = nullptr;
  u16 *Oh = nullptr, *Ol = nullptr;
  int kbeg, kend;
  if (SPLITK == 1) {
    Ah = Ahb + (long)blockIdx.z * az;
    Al = Alb + (long)blockIdx.z * az;
    if (Ob) O = Ob + (long)blockIdx.z * oz;
    if (Ohb) {
      Oh = Ohb + (long)blockIdx.z * oz;
      Ol = Olb + (long)blockIdx.z * oz;
    }
    kbeg = 0;
    kend = K;
  } else {
    Ah = Ahb;
    Al = Alb;
    O = Ob;
    const int ch = K / SPLITK;
    kbeg = blockIdx.z * ch;
    kend = kbeg + ch;
  }
  const int n0 = blockIdx.x * 128;
  const int m0 = blockIdx.y * 64;
  const int tid = threadIdx.x;
  const int lane = tid & 63;
  const int wave = tid >> 6;
  const int wm = wave & 1;
  const int wn = wave >> 1;
  const int r15 = lane & 15;
  const int q8 = (lane >> 4) << 3;
  const int quad4 = (lane >> 4) << 2;

  __shared__ u16 As_h[64 * 40], As_l[64 * 40];
  __shared__ u16 Bs_h[128 * 40], Bs_l[128 * 40];

  f32x4 acc[2][4];
#pragma unroll
  for (int i = 0; i < 2; ++i)
#pragma unroll
    for (int j = 0; j < 4; ++j) acc[i][j] = (f32x4){0.f, 0.f, 0.f, 0.f};

  const int a_row = tid >> 2;          // 0..63
  const int a_kq = (tid & 3) << 3;     // 0,8,16,24
  const int b_row = tid >> 1;          // 0..127
  const int b_kq = (tid & 1) << 4;     // 0,16

  for (int k0 = kbeg; k0 < kend; k0 += 32) {
    const bf16x8 avh = *(const bf16x8*)(Ah + (long)(m0 + a_row) * K + k0 + a_kq);
    const bf16x8 avl = *(const bf16x8*)(Al + (long)(m0 + a_row) * K + k0 + a_kq);
    const long wb = (long)(n0 + b_row) * K + k0 + b_kq;
    const bf16x8 bvh0 = *(const bf16x8*)(Wth + wb);
    const bf16x8 bvh1 = *(const bf16x8*)(Wth + wb + 8);
    const bf16x8 bvl0 = *(const bf16x8*)(Wtl + wb);
    const bf16x8 bvl1 = *(const bf16x8*)(Wtl + wb + 8);
    __syncthreads();
    *(bf16x8*)&As_h[a_row * 40 + a_kq] = avh;
    *(bf16x8*)&As_l[a_row * 40 + a_kq] = avl;
    *(bf16x8*)&Bs_h[b_row * 40 + b_kq] = bvh0;
    *(bf16x8*)&Bs_h[b_row * 40 + b_kq + 8] = bvh1;
    *(bf16x8*)&Bs_l[b_row * 40 + b_kq] = bvl0;
    *(bf16x8*)&Bs_l[b_row * 40 + b_kq + 8] = bvl1;
    __syncthreads();
    bf16x8 ah[2], al[2], bh[4], bl[4];
#pragma unroll
    for (int i = 0; i < 2; ++i) {
      const int ao = (wm * 32 + i * 16 + r15) * 40 + q8;
      ah[i] = *(const bf16x8*)&As_h[ao];
      al[i] = *(const bf16x8*)&As_l[ao];
    }
#pragma unroll
    for (int j = 0; j < 4; ++j) {
      const int bo = (wn * 64 + j * 16 + r15) * 40 + q8;
      bh[j] = *(const bf16x8*)&Bs_h[bo];
      bl[j] = *(const bf16x8*)&Bs_l[bo];
    }
#pragma unroll
    for (int i = 0; i < 2; ++i)
#pragma unroll
      for (int j = 0; j < 4; ++j) {
        acc[i][j] = __builtin_amdgcn_mfma_f32_16x16x32_bf16(ah[i], bh[j], acc[i][j], 0, 0, 0);
        acc[i][j] = __builtin_amdgcn_mfma_f32_16x16x32_bf16(ah[i], bl[j], acc[i][j], 0, 0, 0);
        acc[i][j] = __builtin_amdgcn_mfma_f32_16x16x32_bf16(al[i], bh[j], acc[i][j], 0, 0, 0);
      }
  }

#pragma unroll
  for (int i = 0; i < 2; ++i) {
#pragma unroll
    for (int j = 0; j < 4; ++j) {
      const int col = n0 + wn * 64 + j * 16 + r15;
      const int rbase = m0 + wm * 32 + i * 16 + quad4;
      const float bv = bias ? bias[col] : 0.f;
#pragma unroll
      for (int r = 0; r < 4; ++r) {
        float v = acc[i][j][r];
        if (SPLITK == 1) {
          v += bv;
          if (EP == 1) v = fmaxf(v, 0.f);
          if (EP == 2) v = tanhf(v);
          if (OUTBF) {
            const u16 hi = f2bf(v);
            Oh[(long)(rbase + r) * ldo + col] = hi;
            Ol[(long)(rbase + r) * ldo + col] = f2bf(v - bf2f(hi));
          } else {
            O[(long)(rbase + r) * ldo + col] = v;
          }
        } else {
          if (blockIdx.z == 0) v += bv;
          atomicAdd(&O[(long)(rbase + r) * ldo + col], v);
        }
      }
    }
  }
}

// ---------------- fp32 GEMM (K=16 eagg accumulate): O = A@W + addp ----------------
__launch_bounds__(256) __global__
void gemm_k(const float* __restrict__ Abase, long az,
            const float* __restrict__ W,
            const float* __restrict__ addbase, long adz,
            float* __restrict__ Obase, long oz, int K, int Nc, int ldo) {
  const float* A = Abase + (long)blockIdx.z * az;
  const float* addp = addbase + (long)blockIdx.z * adz;
  float* O = Obase + (long)blockIdx.z * oz;
  const int n0 = blockIdx.x * 64;
  const int m0 = blockIdx.y * 64;
  const int tid = threadIdx.x;
  const int tx = tid & 15, ty = tid >> 4;
  __shared__ float As[16][64];
  __shared__ float Ws[16][64];
  float acc[4][4] = {{0.f, 0.f, 0.f, 0.f}, {0.f, 0.f, 0.f, 0.f},
                     {0.f, 0.f, 0.f, 0.f}, {0.f, 0.f, 0.f, 0.f}};
  const int ar = tid >> 2;
  const int ak = (tid & 3) << 2;
  const int wr = tid >> 4;
  const int wc = (tid & 15) << 2;
  for (int k0 = 0; k0 < K; k0 += 16) {
    const float4 av = *(const float4*)(A + (long)(m0 + ar) * K + k0 + ak);
    const float4 wv = *(const float4*)(W + (long)(k0 + wr) * Nc + n0 + wc);
    __syncthreads();
    As[ak + 0][ar] = av.x;
    As[ak + 1][ar] = av.y;
    As[ak + 2][ar] = av.z;
    As[ak + 3][ar] = av.w;
    *(float4*)(&Ws[wr][wc]) = wv;
    __syncthreads();
#pragma unroll
    for (int kk = 0; kk < 16; ++kk) {
      const float4 a4 = *(const float4*)(&As[kk][ty << 2]);
      const float4 b4 = *(const float4*)(&Ws[kk][tx << 2]);
      const float aa[4] = {a4.x, a4.y, a4.z, a4.w};
      const float bb[4] = {b4.x, b4.y, b4.z, b4.w};
#pragma unroll
      for (int i = 0; i < 4; ++i)
#pragma unroll
        for (int j = 0; j < 4; ++j) acc[i][j] = fmaf(aa[i], bb[j], acc[i][j]);
    }
  }
#pragma unroll
  for (int i = 0; i < 4; ++i) {
    const int m = m0 + (ty << 2) + i;
    float o[4];
#pragma unroll
    for (int j = 0; j < 4; ++j)
      o[j] = acc[i][j] + addp[(long)m * ldo + n0 + (tx << 2) + j];
    *(float4*)(O + (long)m * ldo + n0 + (tx << 2)) = make_float4(o[0], o[1], o[2], o[3]);
  }
}

// ---------------- CSR build ----------------
__global__ void deg_k(const int* __restrict__ eib, int* __restrict__ deg, int t0) {
  const int z = blockIdx.y;
  const int e = blockIdx.x * 256 + threadIdx.x;
  const int dst = eib[(long)(t0 + z) * 2 * E_ + E_ + e];
  atomicAdd(&deg[z * N_ + dst], 1);
}

__launch_bounds__(256) __global__
void scan_k(const int* __restrict__ deg, int* __restrict__ offs, int* __restrict__ cursor) {
  const int z = blockIdx.x, tid = threadIdx.x;
  const int* d = deg + (long)z * N_;
  const int base = tid * 25;
  int loc[25];
  int s = 0;
#pragma unroll
  for (int i = 0; i < 25; ++i) {
    loc[i] = s;
    s += d[base + i];
  }
  __shared__ int ps[256];
  ps[tid] = s;
  __syncthreads();
  for (int off = 1; off < 256; off <<= 1) {
    int v = 0;
    if (tid >= off) v = ps[tid - off];
    __syncthreads();
    if (tid >= off) ps[tid] += v;
    __syncthreads();
  }
  const int pre = (tid == 0) ? 0 : ps[tid - 1];
#pragma unroll
  for (int i = 0; i < 25; ++i) {
    const int o = pre + loc[i];
    offs[(long)z * (N_ + 1) + base + i] = o;
    cursor[(long)z * N_ + base + i] = o;
  }
  if (tid == 255) offs[(long)z * (N_ + 1) + N_] = ps[255];
}

__global__ void fill_k(const int* __restrict__ eib, int* __restrict__ cursor,
                       int* __restrict__ elist, int* __restrict__ srcs, int t0) {
  const int z = blockIdx.y;
  const int e = blockIdx.x * 256 + threadIdx.x;
  const int* base = eib + (long)(t0 + z) * 2 * E_;
  const int src = base[e];
  const int dst = base[E_ + e];
  const int slot = atomicAdd(&cursor[z * N_ + dst], 1);
  elist[(long)z * E_ + slot] = e;
  srcs[(long)z * E_ + slot] = src;
}

__global__ void bounds_k(const int* __restrict__ batchb, int* __restrict__ gb, int t0) {
  const int z = blockIdx.x;
  const int g = threadIdx.x;
  if (g > B_) return;
  const int* bt = batchb + (long)(t0 + z) * N_;
  int lo = 0, hi = N_;
  while (lo < hi) {
    const int mid = (lo + hi) >> 1;
    if (bt[mid] < g) lo = mid + 1; else hi = mid;
  }
  gb[z * (B_ + 1) + g] = lo;
}

// ---------------- per-node mean of edge attrs ----------------
__launch_bounds__(256) __global__
void eagg_k(const float* __restrict__ eab, const int* __restrict__ elist,
            const int* __restrict__ offs, float* __restrict__ eaggc, int t0) {
  const int z = blockIdx.y;
  const int ln = threadIdx.x >> 4;
  const int c = threadIdx.x & 15;
  const int n = blockIdx.x * 16 + ln;
  const int beg = offs[(long)z * (N_ + 1) + n];
  const int end = offs[(long)z * (N_ + 1) + n + 1];
  const float* ea = eab + (long)(t0 + z) * E_ * ED_;
  const int* el = elist + (long)z * E_;
  float v = 0.f;
  for (int j = beg; j < end; ++j) v += ea[(long)el[j] * ED_ + c];
  eaggc[((long)z * N_ + n) * ED_ + c] = v / fmaxf((float)(end - beg), 1.f);
}

// ---------------- fused conv gather: reads fused F[M][512] (xw|pre), LN, bf16 out ----
__launch_bounds__(256) __global__
void conv_gather_k(const float* __restrict__ F, const int* __restrict__ srcs,
                   const int* __restrict__ offs, const float* __restrict__ g,
                   const float* __restrict__ bb, u16* __restrict__ outh,
                   u16* __restrict__ outl) {
  const int z = blockIdx.y;
  const int wid = threadIdx.x >> 6;
  const int lane = threadIdx.x & 63;
  const int n = blockIdx.x * 4 + wid;
  const int beg = offs[(long)z * (N_ + 1) + n];
  const int end = offs[(long)z * (N_ + 1) + n + 1];
  const int* sp = srcs + (long)z * E_;
  const float* Fz = F + (long)z * N_ * 512;
  const int co = lane << 2;
  float4 v = make_float4(0.f, 0.f, 0.f, 0.f);
  int j = beg;
  for (; j + 1 < end; j += 2) {
    const int s0 = sp[j], s1 = sp[j + 1];
    const float4 a = *(const float4*)(Fz + (long)s0 * 512 + co);
    const float4 b2 = *(const float4*)(Fz + (long)s1 * 512 + co);
    v.x += a.x + b2.x;
    v.y += a.y + b2.y;
    v.z += a.z + b2.z;
    v.w += a.w + b2.w;
  }
  if (j < end) {
    const float4 a = *(const float4*)(Fz + (long)sp[j] * 512 + co);
    v.x += a.x;
    v.y += a.y;
    v.z += a.z;
    v.w += a.w;
  }
  const float inv = 1.f / fmaxf((float)(end - beg), 1.f);
  const float4 p = *(const float4*)(Fz + (long)n * 512 + 256 + co);
  const float o0 = fmaxf(fmaf(v.x, inv, p.x), 0.f);
  const float o1 = fmaxf(fmaf(v.y, inv, p.y), 0.f);
  const float o2 = fmaxf(fmaf(v.z, inv, p.z), 0.f);
  const float o3 = fmaxf(fmaf(v.w, inv, p.w), 0.f);
  float s = o0 + o1 + o2 + o3;
  float q = o0 * o0 + o1 * o1 + o2 * o2 + o3 * o3;
#pragma unroll
  for (int m = 1; m < 64; m <<= 1) {
    s += __shfl_xor(s, m, 64);
    q += __shfl_xor(q, m, 64);
  }
  const float mean = s * (1.f / H_);
  const float var = q * (1.f / H_) - mean * mean;
  const float r = rsqrtf(var + 1e-5f);
  const float4 gg = *(const float4*)(g + co);
  const float4 bv = *(const float4*)(bb + co);
  float o[4];
  o[0] = (o0 - mean) * r * gg.x + bv.x;
  o[1] = (o1 - mean) * r * gg.y + bv.y;
  o[2] = (o2 - mean) * r * gg.z + bv.z;
  o[3] = (o3 - mean) * r * gg.w + bv.w;
  const long row = ((long)z * N_ + n) * H_ + co;
  ushort4 hv, lv;
  hv.x = f2bf(o[0]); lv.x = f2bf(o[0] - bf2f(hv.x));
  hv.y = f2bf(o[1]); lv.y = f2bf(o[1] - bf2f(hv.y));
  hv.z = f2bf(o[2]); lv.z = f2bf(o[2] - bf2f(hv.z));
  hv.w = f2bf(o[3]); lv.w = f2bf(o[3] - bf2f(hv.w));
  *(ushort4*)(outh + row) = hv;
  *(ushort4*)(outl + row) = lv;
}

// ---------------- pooling ----------------
__launch_bounds__(256) __global__
void score_k(const float* __restrict__ tnh, const float* __restrict__ sw,
             const float* __restrict__ sb, float* __restrict__ sbuf) {
  const long z = blockIdx.y;
  const int n = blockIdx.x, c = threadIdx.x;
  float p = tnh[(z * N_ + n) * (long)H_ + c] * sw[c];
  __shared__ float rs[256];
  rs[c] = p;
  __syncthreads();
  for (int s = 128; s > 0; s >>= 1) {
    if (c < s) rs[c] += rs[c + s];
    __syncthreads();
  }
  if (c == 0) sbuf[z * N_ + n] = rs[0] + sb[0];
}

__launch_bounds__(256) __global__
void pool_k(const u16* __restrict__ hh, const u16* __restrict__ hl,
            const float* __restrict__ sbuf, const int* __restrict__ gb,
            float* __restrict__ pooled, int t0) {
  const int z = blockIdx.y;
  const int g = blockIdx.x;
  const int c = threadIdx.x;
  const int beg = gb[z * (B_ + 1) + g];
  const int end = gb[z * (B_ + 1) + g + 1];
  const float* sz = sbuf + (long)z * N_;
  __shared__ float red[256];
  float m = -1e30f;
  for (int i = beg + c; i < end; i += 256) m = fmaxf(m, sz[i]);
  red[c] = m;
  __syncthreads();
  for (int s = 128; s > 0; s >>= 1) {
    if (c < s) red[c] = fmaxf(red[c], red[c + s]);
    __syncthreads();
  }
  m = red[0];
  __syncthreads();
  float sum = 0.f;
  for (int i = beg + c; i < end; i += 256) sum += expf(sz[i] - m);
  red[c] = sum;
  __syncthreads();
  for (int s = 128; s > 0; s >>= 1) {
    if (c < s) red[c] += red[c + s];
    __syncthreads();
  }
  sum = red[0];
  float acc = 0.f;
  for (int i = beg; i < end; ++i) {
    const float w = expf(sz[i] - m);
    const long idx = ((long)z * N_ + i) * H_ + c;
    acc = fmaf(bf2f(hh[idx]) + bf2f(hl[idx]), w, acc);
  }
  pooled[((long)(t0 + z) * B_ + g) * H_ + c] = (sum > 0.f) ? acc / sum : 0.f;
}

// ---------------- transformer ----------------
__global__ void build_seq_k(const float* __restrict__ pooled, const float* __restrict__ cls,
                            const float* __restrict__ pos, float* __restrict__ seq,
                            u16* __restrict__ sh, u16* __restrict__ sl) {
  const int s = blockIdx.x, b = blockIdx.y, c = threadIdx.x;
  const float v0 = (s == 0) ? cls[c] : pooled[(((long)(s - 1)) * B_ + b) * H_ + c];
  const float v = v0 + pos[(long)s * H_ + c];
  const long o = ((long)b * S_ + s) * H_ + c;
  seq[o] = v;
  const u16 hi = f2bf(v);
  sh[o] = hi;
  sl[o] = f2bf(v - bf2f(hi));
}

__launch_bounds__(256) __global__
void attn_k(const float* __restrict__ qkv, u16* __restrict__ oh, u16* __restrict__ ol) {
  const int b = blockIdx.x, h = blockIdx.y;
  __shared__ float qs[S_][DH_], ks[S_][DH_], vs[S_][DH_], att[S_][S_];
  const int tid = threadIdx.x;
  for (int i = tid; i < S_ * DH_; i += 256) {
    const int s = i / DH_, d = i % DH_;
    const long base = ((long)b * S_ + s) * (3 * H_) + h * DH_ + d;
    qs[s][d] = qkv[base];
    ks[s][d] = qkv[base + H_];
    vs[s][d] = qkv[base + 2 * H_];
  }
  __syncthreads();
  for (int i = tid; i < S_ * S_; i += 256) {
    const int r = i / S_, c2 = i % S_;
    float acc = 0.f;
#pragma unroll
    for (int d = 0; d < DH_; ++d) acc = fmaf(qs[r][d], ks[c2][d], acc);
    att[r][c2] = acc * 0.17677669529663687f;
  }
  __syncthreads();
  if (tid < S_) {
    float m = -1e30f;
    for (int j = 0; j < S_; ++j) m = fmaxf(m, att[tid][j]);
    float sum = 0.f;
    for (int j = 0; j < S_; ++j) {
      const float e = expf(att[tid][j] - m);
      att[tid][j] = e;
      sum += e;
    }
    const float inv = 1.f / sum;
    for (int j = 0; j < S_; ++j) att[tid][j] *= inv;
  }
  __syncthreads();
  for (int i = tid; i < S_ * DH_; i += 256) {
    const int s = i / DH_, d = i % DH_;
    float acc = 0.f;
#pragma unroll
    for (int j = 0; j < S_; ++j) acc = fmaf(att[s][j], vs[j][d], acc);
    const long o = ((long)b * S_ + s) * H_ + h * DH_ + d;
    const u16 hi = f2bf(acc);
    oh[o] = hi;
    ol[o] = f2bf(acc - bf2f(hi));
  }
}

__launch_bounds__(256) __global__
void resid_ln_k(float* __restrict__ seq, const float* __restrict__ add,
                const float* __restrict__ g, const float* __restrict__ bb,
                u16* __restrict__ sh, u16* __restrict__ sl) {
  const int row = blockIdx.x, c = threadIdx.x;
  const float v = seq[(long)row * H_ + c] + add[(long)row * H_ + c];
  __shared__ float rs[256], rq[256];
  rs[c] = v;
  rq[c] = v * v;
  __syncthreads();
  for (int s = 128; s > 0; s >>= 1) {
    if (c < s) {
      rs[c] += rs[c + s];
      rq[c] += rq[c + s];
    }
    __syncthreads();
  }
  const float mean = rs[0] * (1.f / H_);
  const float var = rq[0] * (1.f / H_) - mean * mean;
  const float o = (v - mean) * rsqrtf(var + 1e-5f) * g[c] + bb[c];
  const long idx = (long)row * H_ + c;
  seq[idx] = o;
  const u16 hi = f2bf(o);
  sh[idx] = hi;
  sl[idx] = f2bf(o - bf2f(hi));
}

__launch_bounds__(256) __global__
void head_k(const float* __restrict__ seq, const float* __restrict__ hw,
            const float* __restrict__ hb, float* __restrict__ out) {
  const int b = blockIdx.x, c = threadIdx.x;
  const float x = seq[(long)b * S_ * H_ + c];
  __shared__ float rs[256];
  for (int o = 0; o < OUT_; ++o) {
    rs[c] = x * hw[c * OUT_ + o];
    __syncthreads();
    for (int s = 128; s > 0; s >>= 1) {
      if (c < s) rs[c] += rs[c + s];
      __syncthreads();
    }
    if (c == 0) {
      const float v = rs[0] + hb[o];
      out[b * OUT_ + o] = fmaxf(v, 0.f) + log1pf(expf(-fabsf(v)));
    }
    __syncthreads();
  }
}

// ---------------- launcher ----------------
extern "C" void kernel_launch(void* const* d_in, const int* in_sizes, int n_in,
                              void* d_out, int out_size, void* d_ws, size_t ws_size,
                              hipStream_t stream) {
  const float* x = (const float*)d_in[0];
  const float* ea = (const float*)d_in[1];
  const int* ei = (const int*)d_in[2];
  const int* batch = (const int*)d_in[3];
  const float* nw0 = (const float*)d_in[4];
  const float* nb0 = (const float*)d_in[5];
  const float* rw0 = (const float*)d_in[6];
  const float* rb0 = (const float*)d_in[7];
  const float* lg0 = (const float*)d_in[8];
  const float* lb0 = (const float*)d_in[9];
  const float* nw1 = (const float*)d_in[10];
  const float* nb1 = (const float*)d_in[11];
  const float* rw1 = (const float*)d_in[12];
  const float* rb1 = (const float*)d_in[13];
  const float* lg1 = (const float*)d_in[14];
  const float* lb1 = (const float*)d_in[15];
  const float* ppw = (const float*)d_in[16];
  const float* ppb = (const float*)d_in[17];
  const float* psw = (const float*)d_in[18];
  const float* psb = (const float*)d_in[19];
  const float* pos = (const float*)d_in[20];
  const float* cls = (const float*)d_in[21];
  const float* qkvw = (const float*)d_in[22];
  const float* qkvbias = (const float*)d_in[23];
  const float* outw = (const float*)d_in[24];
  const float* outb = (const float*)d_in[25];
  const float* f1w = (const float*)d_in[26];
  const float* f1b = (const float*)d_in[27];
  const float* f2w = (const float*)d_in[28];
  const float* f2b = (const float*)d_in[29];
  const float* l1g = (const float*)d_in[30];
  const float* l1b = (const float*)d_in[31];
  const float* l2g = (const float*)d_in[32];
  const float* l2b = (const float*)d_in[33];
  const float* hw = (const float*)d_in[34];
  const float* hb = (const float*)d_in[35];
  float* out = (float*)d_out;

  // ---- workspace carve ----
  char* cur = (char*)d_ws;
  auto alloc = [&](long bytes) {
    char* p = cur;
    cur += (bytes + 255) & ~255L;
    return (void*)p;
  };
  float* pooled = (float*)alloc((long)T_ * B_ * H_ * 4);
  float* seq = (float*)alloc((long)M_TX * H_ * 4);
  u16* seqh = (u16*)alloc((long)M_TX * H_ * 2);
  u16* seql = (u16*)alloc((long)M_TX * H_ * 2);
  float* qkvbuf = (float*)alloc((long)M_TX * 3 * H_ * 4);
  float* obuf_f = (float*)alloc((long)M_TX * H_ * 4);
  u16* obufh = (u16*)alloc((long)M_TX * H_ * 2);
  u16* obufl = (u16*)alloc((long)M_TX * H_ * 2);
  u16* ffh = (u16*)alloc((long)M_TX * DFF_ * 2);
  u16* ffl = (u16*)alloc((long)M_TX * DFF_ * 2);
  u16* w0ch = (u16*)alloc(512L * 128 * 2);
  u16* w0cl = (u16*)alloc(512L * 128 * 2);
  u16* w1ch = (u16*)alloc(512L * 256 * 2);
  u16* w1cl = (u16*)alloc(512L * 256 * 2);
  u16* ppwh = (u16*)alloc(256L * 256 * 2);
  u16* ppwl = (u16*)alloc(256L * 256 * 2);
  u16* qkvwh = (u16*)alloc((long)L_ * 768 * 256 * 2);
  u16* qkvwl = (u16*)alloc((long)L_ * 768 * 256 * 2);
  u16* outwh = (u16*)alloc((long)L_ * 256 * 256 * 2);
  u16* outwl = (u16*)alloc((long)L_ * 256 * 256 * 2);
  u16* f1wh = (u16*)alloc((long)L_ * 2048 * 256 * 2);
  u16* f1wl = (u16*)alloc((long)L_ * 2048 * 256 * 2);
  u16* f2wh = (u16*)alloc((long)L_ * 256 * 2048 * 2);
  u16* f2wl = (u16*)alloc((long)L_ * 256 * 2048 * 2);
  float* bias0c = (float*)alloc(512 * 4);
  float* bias1c = (float*)alloc(512 * 4);
  const long fixed_used = cur - (char*)d_ws;

  const long perday = (long)N_ * 128 * 2 * 2      // xh/xl
                      + (long)N_ * 512 * 4        // bufF
                      + (long)N_ * 256 * 2 * 2    // bufD planes
                      + (long)N_ * 4              // sbuf
                      + (long)N_ * 16 * 4         // eaggc
                      + (2L * E_ + 3L * N_ + (N_ + 1) + (B_ + 1)) * 4 + 4096;
  int DT = 16;
  while (DT > 1 && (size_t)(fixed_used + (long)DT * perday) > ws_size) DT >>= 1;

  u16* xh = (u16*)alloc((long)DT * N_ * 128 * 2);
  u16* xl = (u16*)alloc((long)DT * N_ * 128 * 2);
  float* bufF = (float*)alloc((long)DT * N_ * 512 * 4);
  u16* bufDh = (u16*)alloc((long)DT * N_ * 256 * 2);
  u16* bufDl = (u16*)alloc((long)DT * N_ * 256 * 2);
  float* sbuf = (float*)alloc((long)DT * N_ * 4);
  float* eaggc = (float*)alloc((long)DT * N_ * 16 * 4);
  int* elist = (int*)alloc((long)DT * E_ * 4);
  int* srcs = (int*)alloc((long)DT * E_ * 4);
  int* offs = (int*)alloc((long)DT * (N_ + 1) * 4);
  int* cursor = (int*)alloc((long)DT * N_ * 4);
  int* deg = (int*)alloc((long)DT * N_ * 4);
  int* gb = (int*)alloc((long)DT * (B_ + 1) * 4);

  auto zero = [&](float* p, long n) {
    zero_k<<<dim3((unsigned)((n + 255) / 256)), 256, 0, stream>>>(p, n);
  };

  // ---- weight prep (once per launch) ----
  wconv_k<<<dim3(16, 8), 256, 0, stream>>>(nw0, 128, 256, w0ch, w0cl, 0, 128);
  wconv_k<<<dim3(16, 8), 256, 0, stream>>>(rw0, 128, 256, w0ch, w0cl, 256, 128);
  wconv_k<<<dim3(16, 16), 256, 0, stream>>>(nw1, 256, 256, w1ch, w1cl, 0, 256);
  wconv_k<<<dim3(16, 16), 256, 0, stream>>>(rw1, 256, 256, w1ch, w1cl, 256, 256);
  wconv_k<<<dim3(16, 16), 256, 0, stream>>>(ppw, 256, 256, ppwh, ppwl, 0, 256);
  for (int l = 0; l < L_; ++l) {
    wconv_k<<<dim3(48, 16), 256, 0, stream>>>(qkvw + (long)l * 256 * 768, 256, 768,
                                              qkvwh + (long)l * 768 * 256,
                                              qkvwl + (long)l * 768 * 256, 0, 256);
    wconv_k<<<dim3(16, 16), 256, 0, stream>>>(outw + (long)l * 256 * 256, 256, 256,
                                              outwh + (long)l * 256 * 256,
                                              outwl + (long)l * 256 * 256, 0, 256);
    wconv_k<<<dim3(128, 16), 256, 0, stream>>>(f1w + (long)l * 256 * 2048, 256, 2048,
                                               f1wh + (long)l * 2048 * 256,
                                               f1wl + (long)l * 2048 * 256, 0, 256);
    wconv_k<<<dim3(16, 128), 256, 0, stream>>>(f2w + (long)l * 2048 * 256, 2048, 256,
                                               f2wh + (long)l * 256 * 2048,
                                               f2wl + (long)l * 256 * 2048, 0, 2048);
  }
  biascat_k<<<1, 512, 0, stream>>>(nb0, rb0, bias0c);
  biascat_k<<<1, 512, 0, stream>>>(nb1, rb1, bias1c);

  for (int t0 = 0; t0 < T_; t0 += DT) {
    const int zc = DT;
    // ----- CSR + bounds + edge-attr agg + x split -----
    zero((float*)deg, (long)zc * N_);
    deg_k<<<dim3(E_ / 256, zc), 256, 0, stream>>>(ei, deg, t0);
    scan_k<<<dim3(zc), 256, 0, stream>>>(deg, offs, cursor);
    fill_k<<<dim3(E_ / 256, zc), 256, 0, stream>>>(ei, cursor, elist, srcs, t0);
    bounds_k<<<dim3(zc), 128, 0, stream>>>(batch, gb, t0);
    eagg_k<<<dim3(N_ / 16, zc), 256, 0, stream>>>(ea, elist, offs, eaggc, t0);
    {
      const long nx = (long)zc * N_ * 128;
      split_k<<<dim3((unsigned)(nx / 256)), 256, 0, stream>>>(
          x + (long)t0 * N_ * IN_, xh, xl, nx);
    }
    // ----- conv layer 0: fused [neigh|root] GEMM -----
    gemm_bf<0, 1, 0><<<dim3(4, N_ / 64, zc), 256, 0, stream>>>(
        xh, xl, (long)N_ * 128, w0ch, w0cl, bias0c, bufF, nullptr, nullptr,
        (long)N_ * 512, 128, 512, 512);
    gemm_k<<<dim3(4, N_ / 64, zc), 256, 0, stream>>>(
        eaggc, (long)N_ * 16, nw0 + (long)IN_ * H_, bufF + 256, (long)N_ * 512,
        bufF + 256, (long)N_ * 512, 16, 256, 512);
    conv_gather_k<<<dim3(N_ / 4, zc), 256, 0, stream>>>(bufF, srcs, offs, lg0, lb0,
                                                        bufDh, bufDl);
    // ----- conv layer 1 -----
    gemm_bf<0, 1, 0><<<dim3(4, N_ / 64, zc), 256, 0, stream>>>(
        bufDh, bufDl, (long)N_ * 256, w1ch, w1cl, bias1c, bufF, nullptr, nullptr,
        (long)N_ * 512, 256, 512, 512);
    gemm_k<<<dim3(4, N_ / 64, zc), 256, 0, stream>>>(
        eaggc, (long)N_ * 16, nw1 + (long)H_ * H_, bufF + 256, (long)N_ * 512,
        bufF + 256, (long)N_ * 512, 16, 256, 512);
    conv_gather_k<<<dim3(N_ / 4, zc), 256, 0, stream>>>(bufF, srcs, offs, lg1, lb1,
                                                        bufDh, bufDl);
    // ----- pooling (proj out aliases bufF) -----
    gemm_bf<2, 1, 0><<<dim3(2, N_ / 64, zc), 256, 0, stream>>>(
        bufDh, bufDl, (long)N_ * 256, ppwh, ppwl, ppb, bufF, nullptr, nullptr,
        (long)N_ * 256, 256, 256, 256);
    score_k<<<dim3(N_, zc), 256, 0, stream>>>(bufF, psw, psb, sbuf);
    pool_k<<<dim3(B_, zc), 256, 0, stream>>>(bufDh, bufDl, sbuf, gb, pooled, t0);
  }

  // ----- temporal transformer -----
  build_seq_k<<<dim3(S_, B_), 256, 0, stream>>>(pooled, cls, pos, seq, seqh, seql);
  for (int l = 0; l < L_; ++l) {
    gemm_bf<0, 1, 0><<<dim3(6, M_TX / 64, 1), 256, 0, stream>>>(
        seqh, seql, 0, qkvwh + (long)l * 768 * 256, qkvwl + (long)l * 768 * 256,
        qkvbias + (long)l * 768, qkvbuf, nullptr, nullptr, 0, 256, 768, 768);
    attn_k<<<dim3(B_, HEADS_), 256, 0, stream>>>(qkvbuf, obufh, obufl);
    gemm_bf<0, 1, 0><<<dim3(2, M_TX / 64, 1), 256, 0, stream>>>(
        obufh, obufl, 0, outwh + (long)l * 256 * 256, outwl + (long)l * 256 * 256,
        outb + (long)l * H_, obuf_f, nullptr, nullptr, 0, 256, 256, 256);
    resid_ln_k<<<dim3(M_TX), 256, 0, stream>>>(seq, obuf_f, l1g + (long)l * H_,
                                               l1b + (long)l * H_, seqh, seql);
    gemm_bf<1, 1, 1><<<dim3(16, M_TX / 64, 1), 256, 0, stream>>>(
        seqh, seql, 0, f1wh + (long)l * 2048 * 256, f1wl + (long)l * 2048 * 256,
        f1b + (long)l * DFF_, nullptr, ffh, ffl, 0, 256, 2048, 2048);
    zero(obuf_f, (long)M_TX * H_);
    gemm_bf<0, 8, 0><<<dim3(2, M_TX / 64, 8), 256, 0, stream>>>(
        ffh, ffl, 0, f2wh + (long)l * 256 * 2048, f2wl + (long)l * 256 * 2048,
        f2b + (long)l * H_, obuf_f, nullptr, nullptr, 0, 2048, 256, 256);
    resid_ln_k<<<dim3(M_TX), 256, 0, stream>>>(seq, obuf_f, l2g + (long)l * H_,
                                               l2b + (long)l * H_, seqh, seql);
  }
  head_k<<<dim3(B_), 256, 0, stream>>>(seq, hw, hb, out);
}